// Round 8
// baseline (354.687 us; speedup 1.0000x reference)
//
#include <hip/hip_runtime.h>

typedef unsigned short u16;
typedef unsigned long long u64;
typedef __attribute__((ext_vector_type(8))) short short8;
typedef __attribute__((ext_vector_type(4))) float f32x4;

#define NN   4096
#define EE   131072
#define ETOT (EE + NN)
#define HH   4
#define IND  3000
#define KP   3008
#define D1   512
#define C1   128
#define C2   16

__device__ __forceinline__ float b2f(u16 u){
  union { unsigned int i; float f; } v; v.i = ((unsigned int)u) << 16; return v.f;
}
__device__ __forceinline__ u16 f2b(float f){
  unsigned int x = __float_as_uint(f);
  unsigned int r = (x + 0x7fffu + ((x >> 16) & 1u)) >> 16;
  return (u16)r;
}
__device__ __forceinline__ float lrelu(float x){ return x > 0.f ? x : 0.2f * x; }

__device__ __forceinline__ void glds16(const void* g, void* l){
  __builtin_amdgcn_global_load_lds(
      (const __attribute__((address_space(1))) unsigned int*)g,
      (__attribute__((address_space(3))) unsigned int*)l, 16, 0, 0);
}

__global__ void zero_out_kernel(float* p, int n){
  int i = blockIdx.x * blockDim.x + threadIdx.x;
  if (i < n) p[i] = 0.f;
}

// ---------------------------------------------------------------------------
// W1 fp32 [3000][512] -> transposed split Whi/Wlo [512][3008] (zeros k>=3000)
// (X is no longer pre-split: gemm reads fp32 directly and splits in-register)
// ---------------------------------------------------------------------------
__global__ __launch_bounds__(256) void cvtW1_kernel(const float* __restrict__ W,
    u16* __restrict__ Whi, u16* __restrict__ Wlo){
  __shared__ float T[64][65];
  int wb = blockIdx.x;
  int kb = wb % 47, nb = wb / 47;
  int k0 = kb * 64, n0 = nb * 64;
  int t = threadIdx.x;
  #pragma unroll
  for (int rr = 0; rr < 4; ++rr){
    int kl = (t >> 4) + rr * 16;
    int nn = (t & 15) * 4;
    int k = k0 + kl;
    float4 v = make_float4(0.f, 0.f, 0.f, 0.f);
    if (k < IND) v = *(const float4*)(W + (size_t)k * D1 + n0 + nn);
    T[kl][nn] = v.x; T[kl][nn+1] = v.y; T[kl][nn+2] = v.z; T[kl][nn+3] = v.w;
  }
  __syncthreads();
  int nloc = t >> 2, kseg = (t & 3) * 16;
  int n = n0 + nloc;
  #pragma unroll
  for (int c2 = 0; c2 < 2; ++c2){
    int kloc = kseg + c2 * 8;
    u16 h8[8], l8[8];
    #pragma unroll
    for (int j = 0; j < 8; ++j){
      float f = T[kloc + j][nloc];
      h8[j] = f2b(f); l8[j] = f2b(f - b2f(h8[j]));
    }
    *(uint4*)(Whi + (size_t)n * KP + k0 + kloc) = *(uint4*)h8;
    *(uint4*)(Wlo + (size_t)n * KP + k0 + kloc) = *(uint4*)l8;
  }
}

// ---------------------------------------------------------------------------
// WM/WS [512,64] fp32 -> transposed+split Wh/Wl [128 n][512 k] bf16 hi/lo
// ---------------------------------------------------------------------------
__global__ __launch_bounds__(256) void cvtW2_kernel(const float* __restrict__ WM,
    const float* __restrict__ WS, u16* __restrict__ Wh, u16* __restrict__ Wl){
  __shared__ float T[64][65];
  int half = blockIdx.y;
  int k0 = blockIdx.x * 64;
  const float* W = half ? WS : WM;
  int t = threadIdx.x;
  #pragma unroll
  for (int p = 0; p < 4; ++p){
    int r = p * 16 + (t >> 4), c4 = (t & 15) * 4;
    float4 v = *(const float4*)(W + (size_t)(k0 + r) * 64 + c4);
    T[r][c4] = v.x; T[r][c4+1] = v.y; T[r][c4+2] = v.z; T[r][c4+3] = v.w;
  }
  __syncthreads();
  #pragma unroll
  for (int p = 0; p < 4; ++p){
    int n = p * 16 + (t >> 4), k4 = (t & 15) * 4;
    u16 h4[4], l4[4];
    #pragma unroll
    for (int j = 0; j < 4; ++j){
      float f = T[k4 + j][n];
      h4[j] = f2b(f); l4[j] = f2b(f - b2f(h4[j]));
    }
    size_t o = (size_t)(half * 64 + n) * 512 + k0 + k4;
    *(ushort4*)(Wh + o) = *(ushort4*)h4;
    *(ushort4*)(Wl + o) = *(ushort4*)l4;
  }
}

// ---------------------------------------------------------------------------
// h = X @ W : split-precision bf16 MFMA v8.
// v7's PROVEN schedule (wave-split-K, counted-vmcnt 2-deep pipeline, raw
// s_barrier) kept verbatim. CHANGE: A is read fp32 DIRECTLY from X via
// glds16 (16 KB/buffer = same LDS bytes as hi+lo), hi/lo split happens
// in-register at fragment-read time (trunc-based, ~28 VALU/frag, hidden
// under 20%-busy VALU). Deletes the 147-MB cvtXW X-pass entirely.
// A-LDS: [64 rows][256B], 16-chunk XOR swizzle (c ^ row&15) — each bank
// receives exactly 32B per wave-read = theoretical minimum (conflict-free).
// Tail k>=3000: A reads clamped in-bounds (finite); W rows there are ZERO.
// ---------------------------------------------------------------------------
__global__ __launch_bounds__(512) void gemm_mfma(const float* __restrict__ Xf,
    const u16* __restrict__ Whi, const u16* __restrict__ Wlo,
    float* __restrict__ Hh){
  __shared__ char smem[2][32768];   // [dbuf][ A fp32 16KB | Bh 8KB | Bl 8KB ]
  int t = threadIdx.x, lane = t & 63;
  int wv = __builtin_amdgcn_readfirstlane(t >> 6);   // 0..7
  int ksw = wv >> 2;            // k-slice of this wave (0/1)
  int wr = (wv >> 1) & 1, wc = wv & 1;
  int bm = blockIdx.x * 64, bn = blockIdx.y * 64;
  f32x4 acc[2][2] = {};
  // A staging: 1024 slots (64 rows x 16 chunks of 16B); thread fills t, t+512
  int ar0 = t >> 4,        ac0 = (t & 15) ^ (ar0 & 15);
  int ar1 = 32 + (t >> 4), ac1 = (t & 15) ^ (ar1 & 15);
  const char* gA0 = (const char*)(Xf + (size_t)(bm + ar0) * IND) + ac0 * 16;
  const char* gA1 = (const char*)(Xf + (size_t)(bm + ar1) * IND) + ac1 * 16;
  const char* gAmax = (const char*)Xf + (size_t)NN * IND * 4 - 16;
  // B staging (verbatim v7): slot t, 512 slots = 64 rows x 8 chunks
  int bsr = t >> 3;
  int bsc = (t & 7) ^ (bsr & 7);
  const char* gBh = (const char*)(Whi + (size_t)(bn + bsr) * KP) + bsc * 16;
  const char* gBl = (const char*)(Wlo + (size_t)(bn + bsr) * KP) + bsc * 16;
  // fragment read offsets; cc fixed by this wave's ks
  int r16 = lane & 15, kq = lane >> 4;
  int cc = ksw * 4 + kq;                      // float-8-group index 0..7
  int aoff0[2], aoff1[2], boff[2];
  #pragma unroll
  for (int m = 0; m < 2; ++m){
    int arow = wr * 32 + m * 16 + r16;
    int c0 = cc * 2, c1 = cc * 2 + 1;
    aoff0[m] = arow * 256 + ((c0 ^ (arow & 15)) * 16);
    aoff1[m] = arow * 256 + ((c1 ^ (arow & 15)) * 16);
  }
  #pragma unroll
  for (int n = 0; n < 2; ++n){
    int brow = wc * 32 + n * 16 + r16;
    boff[n] = brow * 128 + ((cc ^ (brow & 7)) * 16);
  }

  // 4 glds16 per thread per stage (2 A fp32 + Bh + Bl) -> vmcnt granularity 4
  #define STAGE(step, b) do {                                           \
      const char* pa0 = gA0 + (step) * 256; if (pa0 > gAmax) pa0 = gAmax; \
      const char* pa1 = gA1 + (step) * 256; if (pa1 > gAmax) pa1 = gAmax; \
      glds16(pa0, smem[b] + t * 16);                                    \
      glds16(pa1, smem[b] + (t + 512) * 16);                            \
      glds16(gBh + (step) * 128, smem[b] + 16384 + t * 16);             \
      glds16(gBl + (step) * 128, smem[b] + 24576 + t * 16);             \
    } while (0)
  #define BARRIER()  asm volatile("s_barrier" ::: "memory")
  #define WAIT_V4()  asm volatile("s_waitcnt vmcnt(4)" ::: "memory")
  #define WAIT_V0()  asm volatile("s_waitcnt vmcnt(0)" ::: "memory")

  STAGE(0, 0);
  STAGE(1, 1);
  WAIT_V4();
  BARRIER();
  for (int i = 0; i < 47; ++i){
    int cur = i & 1;
    const char* pA  = smem[cur];
    const char* pBh = smem[cur] + 16384;
    const char* pBl = smem[cur] + 24576;
    short8 ah[2], al[2], bh[2], bl[2];
    #pragma unroll
    for (int m = 0; m < 2; ++m){
      float4 fa = *(const float4*)(pA + aoff0[m]);
      float4 fb = *(const float4*)(pA + aoff1[m]);
      float f[8] = { fa.x, fa.y, fa.z, fa.w, fb.x, fb.y, fb.z, fb.w };
      unsigned hw[4], lw[4];
      #pragma unroll
      for (int p = 0; p < 4; ++p){
        unsigned u0 = __float_as_uint(f[2*p]);
        unsigned u1 = __float_as_uint(f[2*p+1]);
        unsigned m0 = u0 & 0xffff0000u, m1 = u1 & 0xffff0000u;
        hw[p] = (m0 >> 16) | m1;
        float l0 = f[2*p]   - __uint_as_float(m0);
        float l1 = f[2*p+1] - __uint_as_float(m1);
        lw[p] = (__float_as_uint(l0) >> 16) | (__float_as_uint(l1) & 0xffff0000u);
      }
      ah[m] = *(short8*)hw;
      al[m] = *(short8*)lw;
    }
    #pragma unroll
    for (int n = 0; n < 2; ++n){
      bh[n] = *(const short8*)(pBh + boff[n]);
      bl[n] = *(const short8*)(pBl + boff[n]);
    }
    #pragma unroll
    for (int m = 0; m < 2; ++m)
      #pragma unroll
      for (int n = 0; n < 2; ++n){
        acc[m][n] = __builtin_amdgcn_mfma_f32_16x16x32_bf16(ah[m], bh[n], acc[m][n], 0, 0, 0);
        acc[m][n] = __builtin_amdgcn_mfma_f32_16x16x32_bf16(ah[m], bl[n], acc[m][n], 0, 0, 0);
        acc[m][n] = __builtin_amdgcn_mfma_f32_16x16x32_bf16(al[m], bh[n], acc[m][n], 0, 0, 0);
      }
    BARRIER();
    if (i + 2 < 47){
      STAGE(i + 2, cur);
      WAIT_V4();
    } else {
      WAIT_V0();
    }
    BARRIER();
  }
  #undef STAGE
  #undef BARRIER
  #undef WAIT_V4
  #undef WAIT_V0
  // merge K-halves (verbatim v7)
  float* red = (float*)smem;
  int pp = wr * 2 + wc;
  if (ksw){
    #pragma unroll
    for (int m = 0; m < 2; ++m)
      #pragma unroll
      for (int n = 0; n < 2; ++n)
        #pragma unroll
        for (int r = 0; r < 4; ++r)
          red[((((m*2+n)*4 + r) << 8) + (pp << 6)) + lane] = acc[m][n][r];
  }
  __syncthreads();
  if (!ksw){
    #pragma unroll
    for (int m = 0; m < 2; ++m)
      #pragma unroll
      for (int n = 0; n < 2; ++n){
        #pragma unroll
        for (int r = 0; r < 4; ++r)
          acc[m][n][r] += red[((((m*2+n)*4 + r) << 8) + (pp << 6)) + lane];
        int row = bm + wr * 32 + m * 16 + kq * 4;
        int col = bn + wc * 32 + n * 16 + r16;
        float* o = Hh + (size_t)row * D1 + col;
        #pragma unroll
        for (int r = 0; r < 4; ++r) o[(size_t)r * D1] = acc[m][n][r];
      }
  }
}

// ---------------------------------------------------------------------------
// FALLBACK GEMM (proven): in-kernel split, 64x64 tile
// ---------------------------------------------------------------------------
__global__ __launch_bounds__(256) void gemm_h_split(const float* __restrict__ X,
    const float* __restrict__ Wc, float* __restrict__ Hh){
  __shared__ u16 Ahs[64][40], Als[64][40], Bhs[64][40], Bls[64][40];
  int t = threadIdx.x, lane = t & 63, wave = t >> 6;
  int wr = wave >> 1, wcc = wave & 1;
  int bm = blockIdx.x * 64, bn = blockIdx.y * 64;
  f32x4 acc[2][2] = {};
  int arow = t >> 2, akc = (t & 3) << 3;
  int brow = t >> 3, bnc = (t & 7) << 3;
  for (int k0 = 0; k0 < IND; k0 += 32){
    float va[8];
    size_t abase = (size_t)(bm + arow) * IND + k0 + akc;
    if (k0 + akc + 8 <= IND){
      float4 r0 = *(const float4*)(X + abase);
      float4 r1 = *(const float4*)(X + abase + 4);
      va[0]=r0.x; va[1]=r0.y; va[2]=r0.z; va[3]=r0.w;
      va[4]=r1.x; va[5]=r1.y; va[6]=r1.z; va[7]=r1.w;
    } else {
      #pragma unroll
      for (int j = 0; j < 8; ++j){
        int k = k0 + akc + j;
        va[j] = (k < IND) ? X[abase + j] : 0.f;
      }
    }
    #pragma unroll
    for (int j = 0; j < 8; ++j){
      u16 hb = f2b(va[j]);
      Ahs[arow][akc + j] = hb;
      Als[arow][akc + j] = f2b(va[j] - b2f(hb));
    }
    {
      int gk = k0 + brow;
      float vb[8];
      if (gk < IND){
        const float* wp = Wc + (size_t)gk * D1 + bn + bnc;
        float4 r0 = *(const float4*)wp;
        float4 r1 = *(const float4*)(wp + 4);
        vb[0]=r0.x; vb[1]=r0.y; vb[2]=r0.z; vb[3]=r0.w;
        vb[4]=r1.x; vb[5]=r1.y; vb[6]=r1.z; vb[7]=r1.w;
      } else {
        #pragma unroll
        for (int j = 0; j < 8; ++j) vb[j] = 0.f;
      }
      #pragma unroll
      for (int j = 0; j < 8; ++j){
        u16 hb = f2b(vb[j]);
        Bhs[bnc + j][brow] = hb;
        Bls[bnc + j][brow] = f2b(vb[j] - b2f(hb));
      }
    }
    __syncthreads();
    int r16 = lane & 15, kq = (lane >> 4) << 3;
    short8 a0h = *(const short8*)&Ahs[wr*32      + r16][kq];
    short8 a1h = *(const short8*)&Ahs[wr*32 + 16 + r16][kq];
    short8 a0l = *(const short8*)&Als[wr*32      + r16][kq];
    short8 a1l = *(const short8*)&Als[wr*32 + 16 + r16][kq];
    short8 b0h = *(const short8*)&Bhs[wcc*32      + r16][kq];
    short8 b1h = *(const short8*)&Bhs[wcc*32 + 16 + r16][kq];
    short8 b0l = *(const short8*)&Bls[wcc*32      + r16][kq];
    short8 b1l = *(const short8*)&Bls[wcc*32 + 16 + r16][kq];
    acc[0][0] = __builtin_amdgcn_mfma_f32_16x16x32_bf16(a0h, b0h, acc[0][0], 0, 0, 0);
    acc[0][1] = __builtin_amdgcn_mfma_f32_16x16x32_bf16(a0h, b1h, acc[0][1], 0, 0, 0);
    acc[1][0] = __builtin_amdgcn_mfma_f32_16x16x32_bf16(a1h, b0h, acc[1][0], 0, 0, 0);
    acc[1][1] = __builtin_amdgcn_mfma_f32_16x16x32_bf16(a1h, b1h, acc[1][1], 0, 0, 0);
    acc[0][0] = __builtin_amdgcn_mfma_f32_16x16x32_bf16(a0h, b0l, acc[0][0], 0, 0, 0);
    acc[0][1] = __builtin_amdgcn_mfma_f32_16x16x32_bf16(a0h, b1l, acc[0][1], 0, 0, 0);
    acc[1][0] = __builtin_amdgcn_mfma_f32_16x16x32_bf16(a1h, b0l, acc[1][0], 0, 0, 0);
    acc[1][1] = __builtin_amdgcn_mfma_f32_16x16x32_bf16(a1h, b1l, acc[1][1], 0, 0, 0);
    acc[0][0] = __builtin_amdgcn_mfma_f32_16x16x32_bf16(a0l, b0h, acc[0][0], 0, 0, 0);
    acc[0][1] = __builtin_amdgcn_mfma_f32_16x16x32_bf16(a0l, b1h, acc[0][1], 0, 0, 0);
    acc[1][0] = __builtin_amdgcn_mfma_f32_16x16x32_bf16(a1l, b0h, acc[1][0], 0, 0, 0);
    acc[1][1] = __builtin_amdgcn_mfma_f32_16x16x32_bf16(a1l, b1h, acc[1][1], 0, 0, 0);
    __syncthreads();
  }
  int cr = (lane >> 4) << 2, cc = lane & 15;
  for (int i = 0; i < 2; ++i) for (int j = 0; j < 2; ++j){
    int row = bm + wr*32 + i*16 + cr;
    int col = bn + wcc*32 + j*16 + cc;
    float* o = Hh + (size_t)row * D1 + col;
    for (int r = 0; r < 4; ++r) o[(size_t)r * D1] = acc[i][j][r];
  }
}

// ---------------------------------------------------------------------------
// h [4096,512] fp32 -> h16 bf16 (elementwise)
// ---------------------------------------------------------------------------
__global__ __launch_bounds__(256) void cvt_h16(const float* __restrict__ h,
    u16* __restrict__ h16){
  size_t i = ((size_t)blockIdx.x * 256 + threadIdx.x) * 8;
  float4 va = *(const float4*)(h + i);
  float4 vb = *(const float4*)(h + i + 4);
  u16 q[8] = { f2b(va.x), f2b(va.y), f2b(va.z), f2b(va.w),
               f2b(vb.x), f2b(vb.y), f2b(vb.z), f2b(vb.w) };
  *(uint4*)(h16 + i) = *(uint4*)q;
}

// ---------------------------------------------------------------------------
// layer-1 logits, vectorized
// ---------------------------------------------------------------------------
__global__ __launch_bounds__(256) void evec128(const float* __restrict__ hsrc,
    const float* __restrict__ as_, const float* __restrict__ ad_,
    float* __restrict__ es, float* __restrict__ ed){
  int idx = blockIdx.x * 256 + threadIdx.x;
  if (idx >= NN * HH) return;
  int h = idx & 3;
  const float4* hp = (const float4*)(hsrc + (size_t)idx * C1);
  const float4* ap = (const float4*)(as_ + h * C1);
  const float4* dp = (const float4*)(ad_ + h * C1);
  float s1 = 0.f, s2 = 0.f;
  #pragma unroll
  for (int c = 0; c < 32; ++c){
    float4 v = hp[c], a = ap[c], d = dp[c];
    s1 += v.x*a.x + v.y*a.y + v.z*a.z + v.w*a.w;
    s2 += v.x*d.x + v.y*d.y + v.z*d.z + v.w*d.w;
  }
  es[idx] = s1; ed[idx] = s2;
}

// ---------------------------------------------------------------------------
// CSR build
// ---------------------------------------------------------------------------
__global__ void zero_kernel(int* p, int n){
  int i = blockIdx.x * blockDim.x + threadIdx.x;
  if (i < n) p[i] = 0;
}
__global__ void hist_kernel(const int* __restrict__ dstA, int* __restrict__ deg){
  int e = blockIdx.x * blockDim.x + threadIdx.x;
  if (e < ETOT){
    int d = (e < EE) ? dstA[e] : (e - EE);
    atomicAdd(&deg[d & (NN-1)], 1);
  }
}
__global__ __launch_bounds__(1024) void scan_kernel(const int* __restrict__ deg,
    int* __restrict__ off, int* __restrict__ cur){
  __shared__ int wsum[16];
  int t = threadIdx.x, lane = t & 63, wv = t >> 6;
  int v0 = deg[t*4], v1 = deg[t*4+1], v2 = deg[t*4+2], v3 = deg[t*4+3];
  int s = v0 + v1 + v2 + v3;
  int sc = s;
  #pragma unroll
  for (int o = 1; o < 64; o <<= 1){
    int y = __shfl_up(sc, o);
    if (lane >= o) sc += y;
  }
  if (lane == 63) wsum[wv] = sc;
  __syncthreads();
  int base = 0;
  #pragma unroll
  for (int i = 0; i < 16; ++i) base += (i < wv) ? wsum[i] : 0;
  int excl = base + sc - s;
  int a0 = excl, a1 = a0 + v0, a2 = a1 + v1, a3 = a2 + v2;
  off[t*4] = a0; off[t*4+1] = a1; off[t*4+2] = a2; off[t*4+3] = a3;
  cur[t*4] = a0; cur[t*4+1] = a1; cur[t*4+2] = a2; cur[t*4+3] = a3;
  if (t == 1023) off[4096] = base + sc;
}
__global__ void scatter_kernel(const int* __restrict__ srcA, const int* __restrict__ dstA,
    int* __restrict__ cur, int* __restrict__ sidx){
  int e = blockIdx.x * blockDim.x + threadIdx.x;
  if (e < ETOT){
    int s, d;
    if (e < EE){ s = srcA[e]; d = dstA[e]; } else { s = d = e - EE; }
    int pos = atomicAdd(&cur[d & (NN-1)], 1);
    pos = min(max(pos, 0), ETOT - 1);
    sidx[pos] = s & (NN-1);
  }
}

// ---------------------------------------------------------------------------
// sparse layer 1: single pass, unnormalized accumulate, bf16 h gather.
// ---------------------------------------------------------------------------
__global__ __launch_bounds__(256) void sparse1(const u16* __restrict__ h16,
    const float* __restrict__ es, const float* __restrict__ ed,
    const int* __restrict__ off, const int* __restrict__ sidx,
    const float* __restrict__ bias, u16* __restrict__ x1h, u16* __restrict__ x1l){
  int n = blockIdx.x, t = threadIdx.x, w = t >> 6;
  int o0 = off[n], deg = off[n+1] - o0;
  deg = min(max(deg, 0), ETOT);
  float edn = ed[n * HH + w];
  float dsum = 1e-16f, a0 = 0.f, a1 = 0.f;
  for (int e = 0; e < deg; ++e){
    int s = sidx[o0 + e] & (NN-1);
    float we = __expf(lrelu(es[s*HH + w] + edn));
    unsigned pk = *(const unsigned*)(h16 + ((size_t)s << 9) + 2*t);
    a0 = fmaf(we, b2f((u16)(pk & 0xffff)), a0);
    a1 = fmaf(we, b2f((u16)(pk >> 16)), a1);
    dsum += we;
  }
  float inv = 1.0f / dsum;
  float v0 = a0 * inv + bias[2*t];
  float v1 = a1 * inv + bias[2*t + 1];
  u16 h0 = f2b(v0), h1 = f2b(v1);
  u16 l0 = f2b(v0 - b2f(h0)), l1 = f2b(v1 - b2f(h1));
  size_t o = ((size_t)n << 9) + 2*t;
  *(unsigned*)(x1h + o) = (unsigned)h0 | ((unsigned)h1 << 16);
  *(unsigned*)(x1l + o) = (unsigned)l0 | ((unsigned)l1 << 16);
}

// ---------------------------------------------------------------------------
// sparse layer 2: one wave per (node, branch); fp32 gather (direct output)
// ---------------------------------------------------------------------------
struct Sp2 { const float* h[2]; const float* es[2]; const float* ed[2];
             const float* bias[2]; float* out[2]; };
__global__ __launch_bounds__(64) void sparse2(Sp2 a,
    const int* __restrict__ off, const int* __restrict__ sidx){
  int n = blockIdx.x, sel = blockIdx.y;
  int lane = threadIdx.x, hh = lane >> 4;
  const float* hsrc = a.h[sel];
  const float* es = a.es[sel];
  const float* ed = a.ed[sel];
  int o0 = off[n], deg = off[n+1] - o0;
  deg = min(max(deg, 0), ETOT);
  float edn = ed[n * HH + hh];
  float dsum = 1e-16f, acc = 0.f;
  for (int e = 0; e < deg; ++e){
    int s = sidx[o0 + e] & (NN-1);
    float we = __expf(lrelu(es[s*HH + hh] + edn));
    acc = fmaf(we, hsrc[(size_t)s * 64 + lane], acc);
    dsum += we;
  }
  float v = acc / dsum;
  v += __shfl_xor(v, 16);
  v += __shfl_xor(v, 32);
  if (lane < 16) a.out[sel][(size_t)n * C2 + lane] = v * 0.25f + a.bias[sel][lane];
}

// ---------------------------------------------------------------------------
// fused small GEMMs + layer-2 logits — split-bf16 MFMA.
// ---------------------------------------------------------------------------
struct GsA {
  const u16* x1h; const u16* x1l; const u16* x2h; const u16* x2l;
  const u16* Wh; const u16* Wl;
  float* hm1; float* hs1; float* hm2; float* hs2;
  const float* AMS; const float* AMD; const float* ASS; const float* ASD;
  float* em1s; float* em1d; float* es1s; float* es1d;
  float* em2s; float* em2d; float* es2s; float* es2d;
};
__global__ __launch_bounds__(256) void gemm_small_fused(GsA a){
  __shared__ u16 sAh[32*64], sAl[32*64], sBh[128*64], sBl[128*64];  // 40 KB
  int t = threadIdx.x, lane = t & 63;
  int wv = __builtin_amdgcn_readfirstlane(t >> 6);
  int src = blockIdx.y;
  int bm = blockIdx.x * 32;
  const u16* xh = src ? a.x2h : a.x1h;
  const u16* xl = src ? a.x2l : a.x1l;
  f32x4 acc[2][2] = {};
  int sarow = t >> 3, sac = (t & 7) ^ (sarow & 7);
  const char* gAh = (const char*)(xh + (size_t)(bm + sarow) * 512) + sac * 16;
  const char* gAl = (const char*)(xl + (size_t)(bm + sarow) * 512) + sac * 16;
  char* lAh = (char*)sAh + t * 16;
  char* lAl = (char*)sAl + t * 16;
  const char* gBh[4]; const char* gBl[4];
  #pragma unroll
  for (int q = 0; q < 4; ++q){
    int id = q * 256 + t;
    int br = id >> 3, bc = (id & 7) ^ (br & 7);
    gBh[q] = (const char*)(a.Wh + (size_t)br * 512) + bc * 16;
    gBl[q] = (const char*)(a.Wl + (size_t)br * 512) + bc * 16;
  }
  int r16 = lane & 15, kq = lane >> 4;
  int aoff[2][2], boff[2][2];
  #pragma unroll
  for (int m = 0; m < 2; ++m)
    #pragma unroll
    for (int ks = 0; ks < 2; ++ks){
      int arow = m * 16 + r16;
      int cc = ks * 4 + kq;
      aoff[m][ks] = arow * 128 + ((cc ^ (arow & 7)) * 16);
    }
  #pragma unroll
  for (int n = 0; n < 2; ++n)
    #pragma unroll
    for (int ks = 0; ks < 2; ++ks){
      int brow = wv * 32 + n * 16 + r16;
      int cc = ks * 4 + kq;
      boff[n][ks] = brow * 128 + ((cc ^ (brow & 7)) * 16);
    }
  for (int kb = 0; kb < 1024; kb += 128){
    glds16(gAh + kb, lAh);
    glds16(gAl + kb, lAl);
    #pragma unroll
    for (int q = 0; q < 4; ++q){
      glds16(gBh[q] + kb, (char*)sBh + (q * 256 + t) * 16);
      glds16(gBl[q] + kb, (char*)sBl + (q * 256 + t) * 16);
    }
    __syncthreads();
    #pragma unroll
    for (int ks = 0; ks < 2; ++ks){
      short8 ah[2], al[2], bh[2], bl[2];
      #pragma unroll
      for (int m = 0; m < 2; ++m){
        ah[m] = *(const short8*)((const char*)sAh + aoff[m][ks]);
        al[m] = *(const short8*)((const char*)sAl + aoff[m][ks]);
      }
      #pragma unroll
      for (int n = 0; n < 2; ++n){
        bh[n] = *(const short8*)((const char*)sBh + boff[n][ks]);
        bl[n] = *(const short8*)((const char*)sBl + boff[n][ks]);
      }
      #pragma unroll
      for (int m = 0; m < 2; ++m)
        #pragma unroll
        for (int n = 0; n < 2; ++n){
          acc[m][n] = __builtin_amdgcn_mfma_f32_16x16x32_bf16(ah[m], bh[n], acc[m][n], 0, 0, 0);
          acc[m][n] = __builtin_amdgcn_mfma_f32_16x16x32_bf16(ah[m], bl[n], acc[m][n], 0, 0, 0);
          acc[m][n] = __builtin_amdgcn_mfma_f32_16x16x32_bf16(al[m], bh[n], acc[m][n], 0, 0, 0);
        }
    }
    __syncthreads();
  }
  #pragma unroll
  for (int m = 0; m < 2; ++m){
    #pragma unroll
    for (int n = 0; n < 2; ++n){
      int colB = wv * 32 + n * 16;
      int half = colB >> 6;
      int colh = (colB & 63) + r16;
      int hh = (colB & 63) >> 4;
      int row0 = bm + m * 16 + kq * 4;
      float* o = (src ? (half ? a.hs2 : a.hm2) : (half ? a.hs1 : a.hm1))
                 + (size_t)row0 * 64 + colh;
      #pragma unroll
      for (int r = 0; r < 4; ++r) o[(size_t)r * 64] = acc[m][n][r];
      const float* AS = half ? a.ASS : a.AMS;
      const float* AD = half ? a.ASD : a.AMD;
      float av = AS[colh], dv = AD[colh];
      float* esP = src ? (half ? a.es2s : a.em2s) : (half ? a.es1s : a.em1s);
      float* edP = src ? (half ? a.es2d : a.em2d) : (half ? a.es1d : a.em1d);
      #pragma unroll
      for (int r = 0; r < 4; ++r){
        float vs = acc[m][n][r] * av;
        float vd = acc[m][n][r] * dv;
        #pragma unroll
        for (int msk = 1; msk < 16; msk <<= 1){
          vs += __shfl_xor(vs, msk);
          vd += __shfl_xor(vd, msk);
        }
        if (r16 == 0){
          int rw = row0 + r;
          esP[rw * HH + hh] = vs;
          edP[rw * HH + hh] = vd;
        }
      }
    }
  }
}

// ---------------------------------------------------------------------------
// rank-based sort
// ---------------------------------------------------------------------------
struct RkA { const float* in[2]; float* us[2]; int* pm[2]; };
__global__ __launch_bounds__(1024) void rank_kernel(RkA a){
  int sid = blockIdx.y;
  int sel = sid >> 2, h = sid & 3;
  const float* evals = a.in[sel];
  __shared__ u64 K[NN];
  __shared__ int red[1024];
  int t = threadIdx.x;
  for (int i = t; i < NN; i += 1024){
    unsigned x = __float_as_uint(evals[i*HH + h]);
    x = (x & 0x80000000u) ? ~x : (x | 0x80000000u);
    K[i] = ((u64)x << 32) | (unsigned)i;
  }
  __syncthreads();
  int jl = t & 63, sp = t >> 6;
  int j = blockIdx.x * 64 + jl;
  u64 myk = K[j];
  int cnt = 0;
  int k0 = sp * 256;
  #pragma unroll 8
  for (int i = 0; i < 256; ++i)
    cnt += (K[k0 + i] < myk) ? 1 : 0;
  red[t] = cnt;
  __syncthreads();
  if (sp == 0){
    int rank = 0;
    #pragma unroll
    for (int s = 0; s < 16; ++s) rank += red[jl + 64*s];
    a.us[sel][h*NN + rank] = evals[j*HH + h];
    a.pm[sel][h*NN + rank] = j;
  }
}

// ---------------------------------------------------------------------------
// prefix path v2: row-parallel two-pass scan with COALESCED P writes.
// ---------------------------------------------------------------------------
struct PfxN { const float* hsrc[2]; const int* pm[2]; const float* us[2];
              float* T1; float* T2; float* P1[2]; float* P2[2]; };

template<int C, int CW, int G, int KPER, int NCH>
__global__ __launch_bounds__(512) void pfx_tot(PfxN a){
  constexpr int Cp = C + 1;
  constexpr int CHUNK = G * KPER;
  constexpr int L = G * NCH;
  __shared__ float E1[CHUNK], E2[CHUNK];
  __shared__ int PM[CHUNK];
  int sel = blockIdx.y;
  int h = blockIdx.x / NCH, ch = blockIdx.x % NCH;
  int tid = threadIdx.x;
  const float* us = a.us[sel] + h * NN + ch * CHUNK;
  const int* pm = a.pm[sel] + h * NN + ch * CHUNK;
  for (int tt = tid; tt < CHUNK; tt += 512){
    float u = us[tt];
    E1[tt] = __expf(u); E2[tt] = __expf(0.2f * u);
    PM[tt] = pm[tt] & (NN - 1);
  }
  __syncthreads();
  int g = tid / C, c = tid % C;
  const float* hs = a.hsrc[sel];
  float s1 = 0.f, s2 = 0.f, d1 = 0.f, d2 = 0.f;
  #pragma unroll
  for (int j = 0; j < KPER; ++j){
    int kk = g * KPER + j;
    float v = hs[(size_t)PM[kk] * CW + h * C + c];
    s1 = fmaf(E1[kk], v, s1); s2 = fmaf(E2[kk], v, s2);
    d1 += E1[kk]; d2 += E2[kk];
  }
  int pos = ch * G + g;
  size_t col = (size_t)(sel * HH + h) * Cp + c;
  a.T1[col * L + pos] = s1;
  a.T2[col * L + pos] = s2;
  if (c == 0){
    size_t colD = (size_t)(sel * HH + h) * Cp + C;
    a.T1[colD * L + pos] = d1;
    a.T2[colD * L + pos] = d2;
  }
}

template<int C>
__global__ __launch_bounds__(64) void pfx_scan(PfxN a, int L){
  constexpr int Cp = C + 1;
  int sel = blockIdx.y;
  int col = blockIdx.x;
  int h = col / Cp, c = col % Cp;
  size_t gcol = (size_t)(sel * HH + h) * Cp + c;
  int lane = threadIdx.x;
  float run1 = 0.f, run2 = 0.f;
  for (int p0 = 0; p0 < L; p0 += 64){
    size_t idx = gcol * (size_t)L + p0 + lane;
    float o1 = a.T1[idx], o2 = a.T2[idx];
    float a1 = o1, a2 = o2;
    #pragma unroll
    for (int o = 1; o < 64; o <<= 1){
      float y1 = __shfl_up(a1, o), y2 = __shfl_up(a2, o);
      if (lane >= o){ a1 += y1; a2 += y2; }
    }
    a.T1[idx] = run1 + a1 - o1;
    a.T2[idx] = run2 + a2 - o2;
    run1 += __shfl(a1, 63);
    run2 += __shfl(a2, 63);
  }
  if (lane == 0){
    size_t base = (size_t)h * (NN + 1);
    a.P1[sel][(base + NN) * Cp + c] = run1;
    a.P2[sel][(base + NN) * Cp + c] = run2;
  }
}

template<int C, int CW, int G, int KPER, int NCH>
__global__ __launch_bounds__(512) void pfx_emit(PfxN a){
  constexpr int Cp = C + 1;
  constexpr int CHUNK = G * KPER;
  constexpr int L = G * NCH;
  __shared__ float E1[CHUNK], E2[CHUNK];
  __shared__ int PM[CHUNK];
  int sel = blockIdx.y;
  int h = blockIdx.x / NCH, ch = blockIdx.x % NCH;
  int tid = threadIdx.x;
  const float* us = a.us[sel] + h * NN + ch * CHUNK;
  const int* pm = a.pm[sel] + h * NN + ch * CHUNK;
  for (int tt = tid; tt < CHUNK; tt += 512){
    float u = us[tt];
    E1[tt] = __expf(u); E2[tt] = __expf(0.2f * u);
    PM[tt] = pm[tt] & (NN - 1);
  }
  __syncthreads();
  int g = tid / C, c = tid % C;
  const float* hs = a.hsrc[sel];
  float* P1 = a.P1[sel];
  float* P2 = a.P2[sel];
  int pos = ch * G + g;
  size_t col = (size_t)(sel * HH + h) * Cp + c;
  float r1 = a.T1[col * L + pos];
  float r2 = a.T2[col * L + pos];
  float rD1 = 0.f, rD2 = 0.f;
  if (c == 0){
    size_t colD = (size_t)(sel * HH + h) * Cp + C;
    rD1 = a.T1[colD * L + pos];
    rD2 = a.T2[colD * L + pos];
  }
  size_t hb = (size_t)h * (NN + 1) + ch * CHUNK + g * KPER;
  #pragma unroll
  for (int j = 0; j < KPER; ++j){
    int kk = g * KPER + j;
    float v = hs[(size_t)PM[kk] * CW + h * C + c];
    P1[(hb + j) * Cp + c] = r1;
    P2[(hb + j) * Cp + c] = r2;
    r1 = fmaf(E1[kk], v, r1);
    r2 = fmaf(E2[kk], v, r2);
    if (c == 0){
      P1[(hb + j) * Cp + C] = rD1;
      P2[(hb + j) * Cp + C] = rD2;
      rD1 += E1[kk]; rD2 += E2[kk];
    }
  }
}

// ---------------------------------------------------------------------------
// dense output via separable leaky-relu softmax
// ---------------------------------------------------------------------------
template<int C, bool MEAN>
__device__ __forceinline__ void dense_body(const float* __restrict__ P1,
    const float* __restrict__ P2, const float* __restrict__ usort,
    const float* __restrict__ ed, const float* __restrict__ bias,
    float* __restrict__ outF, u16* __restrict__ outH, u16* __restrict__ outL, int i){
  constexpr int Cp = C + 1;
  constexpr int NC = HH * C;
  int t = threadIdx.x;
  __shared__ float Ed[HH], E2d[HH], Den[HH];
  __shared__ int   Kh[HH];
  __shared__ float vals[NC > 256 ? 1 : NC];
  if (t < HH){
    float d = ed[i*HH + t];
    float target = -d;
    const float* us = usort + t * NN;
    int lo = 0, hi = NN;
    while (lo < hi){ int mid = (lo + hi) >> 1; if (us[mid] < target) lo = mid + 1; else hi = mid; }
    Kh[t] = lo;
    float e1 = __expf(d), e2 = __expf(0.2f * d);
    Ed[t] = e1; E2d[t] = e2;
    size_t base = (size_t)t * (NN + 1);
    float p1N = P1[(base + NN) * Cp + C];
    float p1k = P1[(base + lo) * Cp + C];
    float p2k = P2[(base + lo) * Cp + C];
    Den[t] = e1 * (p1N - p1k) + e2 * p2k;
  }
  __syncthreads();
  if (!MEAN){
    for (int ch = t; ch < NC; ch += 256){
      int h = ch / C, c = ch % C;
      size_t base = (size_t)h * (NN + 1);
      float p1N = P1[(base + NN)    * Cp + c];
      float p1k = P1[(base + Kh[h]) * Cp + c];
      float p2k = P2[(base + Kh[h]) * Cp + c];
      float num = Ed[h] * (p1N - p1k) + E2d[h] * p2k;
      float val = num / Den[h] + bias[ch];
      u16 hb = f2b(val);
      outH[(size_t)i * NC + ch] = hb;
      outL[(size_t)i * NC + ch] = f2b(val - b2f(hb));
    }
  } else {
    if (t < NC){
      int h = t / C, c = t % C;
      size_t base = (size_t)h * (NN + 1);
      float p1N = P1[(base + NN)    * Cp + c];
      float p1k = P1[(base + Kh[h]) * Cp + c];
      float p2k = P2[(base + Kh[h]) * Cp + c];
      vals[t] = (Ed[h] * (p1N - p1k) + E2d[h] * p2k) / Den[h];
    }
    __syncthreads();
    if (t < C){
      float z = (vals[t] + vals[C + t] + vals[2*C + t] + vals[3*C + t]) * 0.25f + bias[t];
      outF[(size_t)i * C + t] = z;
    }
  }
}

__global__ __launch_bounds__(256) void dense_out1(const float* __restrict__ P1,
    const float* __restrict__ P2, const float* __restrict__ usort,
    const float* __restrict__ ed, const float* __restrict__ bias,
    u16* __restrict__ outH, u16* __restrict__ outL){
  dense_body<C1, false>(P1, P2, usort, ed, bias, nullptr, outH, outL, blockIdx.x);
}

struct Dn2 { const float* P1[2]; const float* P2[2]; const float* us[2];
             const float* ed[2]; const float* bias[2]; float* out[2]; };
__global__ __launch_bounds__(256) void dense_out2(Dn2 a){
  int s = blockIdx.y;
  dense_body<C2, true>(a.P1[s], a.P2[s], a.us[s], a.ed[s], a.bias[s], a.out[s],
                       nullptr, nullptr, blockIdx.x);
}

// ---------------------------------------------------------------------------
extern "C" void kernel_launch(void* const* d_in, const int* in_sizes, int n_in,
                              void* d_out, int out_size, void* d_ws, size_t ws_size,
                              hipStream_t stream){
  const float* X   = (const float*)d_in[0];
  const int*   EI  = (const int*)d_in[1];
  const float* W1  = (const float*)d_in[3];
  const float* A1S = (const float*)d_in[4];
  const float* A1D = (const float*)d_in[5];
  const float* B1  = (const float*)d_in[6];
  const float* WM  = (const float*)d_in[7];
  const float* AMS = (const float*)d_in[8];
  const float* AMD = (const float*)d_in[9];
  const float* BM  = (const float*)d_in[10];
  const float* WS  = (const float*)d_in[11];
  const float* ASS = (const float*)d_in[12];
  const float* ASD = (const float*)d_in[13];
  const float* BS  = (const float*)d_in[14];
  float* OUT = (float*)d_out;
  (void)in_sizes; (void)n_in;

  if (ws_size < (size_t)56 * 1024 * 1024){
    zero_out_kernel<<<dim3((out_size + 255)/256), 256, 0, stream>>>(OUT, out_size);
    return;
  }
  bool fast = (ws_size >= (size_t)68 * 1024 * 1024);

  const size_t MB = 1024 * 1024;
  char* w = (char*)d_ws;
  size_t o = 0;
  auto alloc = [&](size_t bytes) -> void* {
    void* p = w + o;
    o += (bytes + 255) & ~(size_t)255;
    return p;
  };
  int*   deg  = (int*)  alloc(NN * 4);
  int*   coff = (int*)  alloc((NN + 1) * 4);
  int*   cur  = (int*)  alloc(NN * 4);
  int*   sidx = (int*)  alloc((size_t)ETOT * 4);
  float* e1s  = (float*)alloc(NN * HH * 4);
  float* e1d  = (float*)alloc(NN * HH * 4);
  float* us1  = (float*)alloc(HH * NN * 4);
  int*   pm1  = (int*)  alloc(HH * NN * 4);
  float* em1s = (float*)alloc(NN * HH * 4);
  float* em1d = (float*)alloc(NN * HH * 4);
  float* es1s = (float*)alloc(NN * HH * 4);
  float* es1d = (float*)alloc(NN * HH * 4);
  float* em2s = (float*)alloc(NN * HH * 4);
  float* em2d = (float*)alloc(NN * HH * 4);
  float* es2s = (float*)alloc(NN * HH * 4);
  float* es2d = (float*)alloc(NN * HH * 4);
  float* us2m = (float*)alloc(HH * NN * 4);
  int*   pm2m = (int*)  alloc(HH * NN * 4);
  float* us2s = (float*)alloc(HH * NN * 4);
  int*   pm2s = (int*)  alloc(HH * NN * 4);
  u16*   Wh2  = (u16*)  alloc(128 * 512 * 2);
  u16*   Wl2  = (u16*)  alloc(128 * 512 * 2);
  float* h    = (float*)alloc((size_t)NN * D1 * 4);
  char*  BIG  = w + o;
  // --- phase A (GEMM W staging, dead after gemm_mfma) ---
  u16* Whi = (u16*)BIG;                         // 512*3008*2 ~ 2.94 MB
  u16* Wlo = (u16*)(BIG + 4*MB);
  // --- phase B (post-GEMM; x1/x2 stored as split bf16 hi/lo) ---
  u16*   x1h = (u16*)  (BIG + 0*MB);
  u16*   x1l = (u16*)  (BIG + 4*MB);
  u16*   x2h = (u16*)  (BIG + 8*MB);
  u16*   x2l = (u16*)  (BIG + 12*MB);
  float* T1a = (float*)(BIG + 16*MB);           // layer-1 prefix totals
  float* T2a = (float*)(BIG + 17*MB);
  u16*   h16 = (u16*)  (BIG + 24*MB);
  float* P1a = (float*)(BIG + 28*MB);
  float* P2a = (float*)(BIG + 37*MB);
  // --- phase C (from gemm_small_fused on) ---
  float* hm1  = (float*)(BIG + 16*MB);
  float* hs1  = (float*)(BIG + 17*MB);
  float* hm2  = (float*)(BIG + 18*MB);
  float* hs2  = (float*)(BIG + 19*MB);
  float* P1m  = (float*)(BIG + 20*MB);
  float* P2m  = (float*)(BIG + 21*MB + 512*1024);
  float* P1s  = (float*)(BIG + 23*MB);
  float* P2s  = (float*)(BIG + 24*MB + 512*1024);
  float* T1b  = (float*)(BIG + 26*MB);          // layer-2 prefix totals
  float* T2b  = (float*)(BIG + 26*MB + 512*1024);

  const int* srcA = EI;
  const int* dstA = EI + EE;

  // 0. small-W conversions
  cvtW2_kernel<<<dim3(8, 2), 256, 0, stream>>>(WM, WS, Wh2, Wl2);
  // 1. h = X @ W1
  if (fast){
    cvtW1_kernel<<<dim3(47*8), 256, 0, stream>>>(W1, Whi, Wlo);
    gemm_mfma<<<dim3(NN/64, D1/64), 512, 0, stream>>>(X, Whi, Wlo, h);
  } else {
    gemm_h_split<<<dim3(NN/64, D1/64), 256, 0, stream>>>(X, W1, h);
  }
  // 2. bf16 copy; layer-1 logits
  cvt_h16<<<dim3(1024), 256, 0, stream>>>(h, h16);
  evec128<<<dim3(NN*HH/256), 256, 0, stream>>>(h, A1S, A1D, e1s, e1d);
  // 3. CSR
  zero_kernel<<<dim3(16), 256, 0, stream>>>(deg, NN);
  hist_kernel<<<dim3((ETOT + 255)/256), 256, 0, stream>>>(dstA, deg);
  scan_kernel<<<dim3(1), 1024, 0, stream>>>(deg, coff, cur);
  scatter_kernel<<<dim3((ETOT + 255)/256), 256, 0, stream>>>(srcA, dstA, cur, sidx);
  // 4. sparse layer 1 -> x1 (split bf16)
  sparse1<<<dim3(NN), 256, 0, stream>>>(h16, e1s, e1d, coff, sidx, B1, x1h, x1l);
  // 5. dense layer 1 -> x2 (split bf16); prefix v2 (coalesced writes)
  {
    RkA ra; ra.in[0] = e1s; ra.in[1] = e1s; ra.us[0] = us1; ra.us[1] = us1;
    ra.pm[0] = pm1; ra.pm[1] = pm1;
    rank_kernel<<<dim3(64, 4), 1024, 0, stream>>>(ra);
    PfxN pa;
    pa.hsrc[0] = h;  pa.hsrc[1] = h;
    pa.pm[0] = pm1;  pa.pm[1] = pm1;
    pa.us[0] = us1;  pa.us[1] = us1;
    pa.T1 = T1a; pa.T2 = T2a;
    pa.P1[0] = P1a; pa.P1[1] = P1a;
    pa.P2[0] = P2a; pa.P2[1] = P2a;
    pfx_tot<C1, D1, 4, 16, 64><<<dim3(HH*64, 1), 512, 0, stream>>>(pa);
    pfx_scan<C1><<<dim3(HH*(C1+1), 1), 64, 0, stream>>>(pa, 256);
    pfx_emit<C1, D1, 4, 16, 64><<<dim3(HH*64, 1), 512, 0, stream>>>(pa);
    dense_out1<<<dim3(NN), 256, 0, stream>>>(P1a, P2a, us1, e1d, B1, x2h, x2l);
  }
  // 6. fused projections + layer-2 logits (split-bf16 MFMA)
  {
    GsA ga;
    ga.x1h = x1h; ga.x1l = x1l; ga.x2h = x2h; ga.x2l = x2l;
    ga.Wh = Wh2; ga.Wl = Wl2;
    ga.hm1 = hm1; ga.hs1 = hs1; ga.hm2 = hm2; ga.hs2 = hs2;
    ga.AMS = AMS; ga.AMD = AMD; ga.ASS = ASS; ga.ASD = ASD;
    ga.em1s = em1s; ga.em1d = em1d; ga.es1s = es1s; ga.es1d = es1d;
    ga.em2s = em2s; ga.em2d = em2d; ga.es2s = es2s; ga.es2d = es2d;
    gemm_small_fused<<<dim3(NN/32, 2), 256, 0, stream>>>(ga);
  }
  // 7. sparse layer 2 -> z_mean1, z_log_std1
  {
    Sp2 sp;
    sp.h[0] = hm1; sp.h[1] = hs1; sp.es[0] = em1s; sp.es[1] = es1s;
    sp.ed[0] = em1d; sp.ed[1] = es1d; sp.bias[0] = BM; sp.bias[1] = BS;
    sp.out[0] = OUT; sp.out[1] = OUT + (size_t)NN*C2;
    sparse2<<<dim3(NN, 2), 64, 0, stream>>>(sp, coff, sidx);
  }
  // 8. dense layer 2 -> z_mean2, z_log_std2; prefix v2
  {
    RkA ra; ra.in[0] = em2s; ra.in[1] = es2s; ra.us[0] = us2m; ra.us[1] = us2s;
    ra.pm[0] = pm2m; ra.pm[1] = pm2s;
    rank_kernel<<<dim3(64, 8), 1024, 0, stream>>>(ra);
    PfxN pa;
    pa.hsrc[0] = hm2; pa.hsrc[1] = hs2;
    pa.pm[0] = pm2m;  pa.pm[1] = pm2s;
    pa.us[0] = us2m;  pa.us[1] = us2s;
    pa.T1 = T1b; pa.T2 = T2b;
    pa.P1[0] = P1m; pa.P1[1] = P1s;
    pa.P2[0] = P2m; pa.P2[1] = P2s;
    pfx_tot<C2, 64, 32, 8, 16><<<dim3(HH*16, 2), 512, 0, stream>>>(pa);
    pfx_scan<C2><<<dim3(HH*(C2+1), 2), 64, 0, stream>>>(pa, 512);
    pfx_emit<C2, 64, 32, 8, 16><<<dim3(HH*16, 2), 512, 0, stream>>>(pa);
    Dn2 dn;
    dn.P1[0] = P1m; dn.P1[1] = P1s; dn.P2[0] = P2m; dn.P2[1] = P2s;
    dn.us[0] = us2m; dn.us[1] = us2s; dn.ed[0] = em2d; dn.ed[1] = es2d;
    dn.bias[0] = BM; dn.bias[1] = BS;
    dn.out[0] = OUT + (size_t)2*NN*C2; dn.out[1] = OUT + (size_t)3*NN*C2;
    dense_out2<<<dim3(NN, 2), 256, 0, stream>>>(dn);
  }
}

// Round 9
// 347.655 us; speedup vs baseline: 1.0202x; 1.0202x over previous
//
#include <hip/hip_runtime.h>

typedef unsigned short u16;
typedef unsigned long long u64;
typedef __attribute__((ext_vector_type(8))) short short8;
typedef __attribute__((ext_vector_type(4))) float f32x4;

#define NN   4096
#define EE   131072
#define ETOT (EE + NN)
#define HH   4
#define IND  3000
#define KP   3008
#define D1   512
#define C1   128
#define C2   16

__device__ __forceinline__ float b2f(u16 u){
  union { unsigned int i; float f; } v; v.i = ((unsigned int)u) << 16; return v.f;
}
__device__ __forceinline__ u16 f2b(float f){
  unsigned int x = __float_as_uint(f);
  unsigned int r = (x + 0x7fffu + ((x >> 16) & 1u)) >> 16;
  return (u16)r;
}
__device__ __forceinline__ float lrelu(float x){ return x > 0.f ? x : 0.2f * x; }

__device__ __forceinline__ void glds16(const void* g, void* l){
  __builtin_amdgcn_global_load_lds(
      (const __attribute__((address_space(1))) unsigned int*)g,
      (__attribute__((address_space(3))) unsigned int*)l, 16, 0, 0);
}

__global__ void zero_out_kernel(float* p, int n){
  int i = blockIdx.x * blockDim.x + threadIdx.x;
  if (i < n) p[i] = 0.f;
}

// ---------------------------------------------------------------------------
// W1 fp32 [3000][512] -> transposed split Whi/Wlo [512][3008] (zeros k>=3000)
// ---------------------------------------------------------------------------
__global__ __launch_bounds__(256) void cvtW1_kernel(const float* __restrict__ W,
    u16* __restrict__ Whi, u16* __restrict__ Wlo){
  __shared__ float T[64][65];
  int wb = blockIdx.x;
  int kb = wb % 47, nb = wb / 47;
  int k0 = kb * 64, n0 = nb * 64;
  int t = threadIdx.x;
  #pragma unroll
  for (int rr = 0; rr < 4; ++rr){
    int kl = (t >> 4) + rr * 16;
    int nn = (t & 15) * 4;
    int k = k0 + kl;
    float4 v = make_float4(0.f, 0.f, 0.f, 0.f);
    if (k < IND) v = *(const float4*)(W + (size_t)k * D1 + n0 + nn);
    T[kl][nn] = v.x; T[kl][nn+1] = v.y; T[kl][nn+2] = v.z; T[kl][nn+3] = v.w;
  }
  __syncthreads();
  int nloc = t >> 2, kseg = (t & 3) * 16;
  int n = n0 + nloc;
  #pragma unroll
  for (int c2 = 0; c2 < 2; ++c2){
    int kloc = kseg + c2 * 8;
    u16 h8[8], l8[8];
    #pragma unroll
    for (int j = 0; j < 8; ++j){
      float f = T[kloc + j][nloc];
      h8[j] = f2b(f); l8[j] = f2b(f - b2f(h8[j]));
    }
    *(uint4*)(Whi + (size_t)n * KP + k0 + kloc) = *(uint4*)h8;
    *(uint4*)(Wlo + (size_t)n * KP + k0 + kloc) = *(uint4*)l8;
  }
}

// ---------------------------------------------------------------------------
// WM/WS [512,64] fp32 -> transposed+split Wh/Wl [128 n][512 k] bf16 hi/lo
// ---------------------------------------------------------------------------
__global__ __launch_bounds__(256) void cvtW2_kernel(const float* __restrict__ WM,
    const float* __restrict__ WS, u16* __restrict__ Wh, u16* __restrict__ Wl){
  __shared__ float T[64][65];
  int half = blockIdx.y;
  int k0 = blockIdx.x * 64;
  const float* W = half ? WS : WM;
  int t = threadIdx.x;
  #pragma unroll
  for (int p = 0; p < 4; ++p){
    int r = p * 16 + (t >> 4), c4 = (t & 15) * 4;
    float4 v = *(const float4*)(W + (size_t)(k0 + r) * 64 + c4);
    T[r][c4] = v.x; T[r][c4+1] = v.y; T[r][c4+2] = v.z; T[r][c4+3] = v.w;
  }
  __syncthreads();
  #pragma unroll
  for (int p = 0; p < 4; ++p){
    int n = p * 16 + (t >> 4), k4 = (t & 15) * 4;
    u16 h4[4], l4[4];
    #pragma unroll
    for (int j = 0; j < 4; ++j){
      float f = T[k4 + j][n];
      h4[j] = f2b(f); l4[j] = f2b(f - b2f(h4[j]));
    }
    size_t o = (size_t)(half * 64 + n) * 512 + k0 + k4;
    *(ushort4*)(Wh + o) = *(ushort4*)h4;
    *(ushort4*)(Wl + o) = *(ushort4*)l4;
  }
}

// ---------------------------------------------------------------------------
// h = X @ W : split-precision bf16 MFMA v9 (reg-staged A split, T14 pattern).
// Compute phase = v7 verbatim (ds_read b128 + MFMA only; NO VALU in the
// dependent chain).  A: global fp32 -> regs (issued one iteration ahead) ->
// split ONCE per element at stage time (v_perm byte-pack, 6 VALU/pair) ->
// ds_write_b128 into v7's exact LDS layout (linear slots = conflict-free
// writes; fragment reads = v7's proven 0-conflict pattern).
// Sync ledger: write-phase reg-use of A(i+2) (FIFO-ordered after B(i+1))
// auto-drains B(i+1) before compute(i+1); lgkmcnt(0) before final barrier
// makes ds_writes visible; i=45 tail drains vmcnt(0).  B staging verbatim.
// Tail k>=3000: A pointers clamped in-bounds (finite); W rows there ZERO.
// ---------------------------------------------------------------------------
__global__ __launch_bounds__(512) void gemm_mfma(const float* __restrict__ Xf,
    const u16* __restrict__ Whi, const u16* __restrict__ Wlo,
    float* __restrict__ Hh){
  __shared__ u16 sbuf[2][4][4096];   // [dbuf][Ah,Al,Bh,Bl] 8 KB each = 64 KB
  int t = threadIdx.x, lane = t & 63;
  int wv = __builtin_amdgcn_readfirstlane(t >> 6);   // 0..7
  int ksw = wv >> 2;
  int wr = (wv >> 1) & 1, wc = wv & 1;
  int bm = blockIdx.x * 64, bn = blockIdx.y * 64;
  f32x4 acc[2][2] = {};
  // staging map (verbatim v7): slot t = (row t>>3, chunk' t&7);
  // global chunk = chunk' ^ (row&7).  A chunk = 8 floats = 32B global.
  int srow = t >> 3;
  int sc = (t & 7) ^ (srow & 7);
  const char* gA  = (const char*)(Xf + (size_t)(bm + srow) * IND) + sc * 32;
  const char* gAend = (const char*)Xf + (size_t)NN * IND * 4 - 16;
  const char* gBh = (const char*)(Whi + (size_t)(bn + srow) * KP) + sc * 16;
  const char* gBl = (const char*)(Wlo + (size_t)(bn + srow) * KP) + sc * 16;
  // fragment read offsets (verbatim v7)
  int r16 = lane & 15, kq = lane >> 4;
  int cc = ksw * 4 + kq;
  int aoff[2], boff[2];
  #pragma unroll
  for (int m = 0; m < 2; ++m){
    int arow = wr * 32 + m * 16 + r16;
    aoff[m] = arow * 128 + ((cc ^ (arow & 7)) * 16);
  }
  #pragma unroll
  for (int n = 0; n < 2; ++n){
    int brow = wc * 32 + n * 16 + r16;
    boff[n] = brow * 128 + ((cc ^ (brow & 7)) * 16);
  }

  float4 ra0, ra1;
  #define LOADA(step) do {                                      \
      const char* p0 = gA + (step) * 256;                       \
      const char* p1 = p0 + 16;                                 \
      if (p0 > gAend) p0 = gAend;                               \
      if (p1 > gAend) p1 = gAend;                               \
      ra0 = *(const float4*)p0;                                 \
      ra1 = *(const float4*)p1;                                 \
    } while (0)
  #define WRITEA(b) do {                                        \
      float ff[8] = { ra0.x, ra0.y, ra0.z, ra0.w,               \
                      ra1.x, ra1.y, ra1.z, ra1.w };             \
      unsigned hw[4], lw[4];                                    \
      _Pragma("unroll")                                         \
      for (int p = 0; p < 4; ++p){                              \
        unsigned u0 = __float_as_uint(ff[2*p]);                 \
        unsigned u1 = __float_as_uint(ff[2*p+1]);               \
        hw[p] = __builtin_amdgcn_perm(u1, u0, 0x07060302u);     \
        float l0 = ff[2*p]   - __uint_as_float(u0 & 0xffff0000u); \
        float l1 = ff[2*p+1] - __uint_as_float(u1 & 0xffff0000u); \
        lw[p] = __builtin_amdgcn_perm(__float_as_uint(l1),      \
                                      __float_as_uint(l0), 0x07060302u); \
      }                                                         \
      *(uint4*)((char*)sbuf[b][0] + t * 16) = *(uint4*)hw;      \
      *(uint4*)((char*)sbuf[b][1] + t * 16) = *(uint4*)lw;      \
    } while (0)
  #define GLDSB(step, b) do {                                   \
      glds16(gBh + (step) * 128, (char*)sbuf[b][2] + t * 16);   \
      glds16(gBl + (step) * 128, (char*)sbuf[b][3] + t * 16);   \
    } while (0)
  #define BARRIER()  asm volatile("s_barrier" ::: "memory")

  // prologue: W(0), W(1) written; A(2) in flight; B(0),B(1) in flight->drained
  LOADA(0);
  WRITEA(0);                 // waits A(0) regs
  LOADA(1);
  GLDSB(0, 0);
  GLDSB(1, 1);
  WRITEA(1);                 // waits A(1) regs (drains nothing of B: B after A1)
  LOADA(2);
  asm volatile("s_waitcnt vmcnt(2) lgkmcnt(0)" ::: "memory");  // B0,B1 done; writes visible
  BARRIER();
  for (int i = 0; i < 47; ++i){
    int cur = i & 1;
    const char* pAh = (const char*)sbuf[cur][0];
    const char* pAl = (const char*)sbuf[cur][1];
    const char* pBh = (const char*)sbuf[cur][2];
    const char* pBl = (const char*)sbuf[cur][3];
    short8 ah[2], al[2], bh[2], bl[2];
    #pragma unroll
    for (int m = 0; m < 2; ++m){
      ah[m] = *(const short8*)(pAh + aoff[m]);
      al[m] = *(const short8*)(pAl + aoff[m]);
    }
    #pragma unroll
    for (int n = 0; n < 2; ++n){
      bh[n] = *(const short8*)(pBh + boff[n]);
      bl[n] = *(const short8*)(pBl + boff[n]);
    }
    #pragma unroll
    for (int m = 0; m < 2; ++m)
      #pragma unroll
      for (int n = 0; n < 2; ++n){
        acc[m][n] = __builtin_amdgcn_mfma_f32_16x16x32_bf16(ah[m], bh[n], acc[m][n], 0, 0, 0);
        acc[m][n] = __builtin_amdgcn_mfma_f32_16x16x32_bf16(ah[m], bl[n], acc[m][n], 0, 0, 0);
        acc[m][n] = __builtin_amdgcn_mfma_f32_16x16x32_bf16(al[m], bh[n], acc[m][n], 0, 0, 0);
      }
    BARRIER();                        // all waves done reading buf[cur]
    if (i + 2 < 47){
      WRITEA(cur);                    // uses A(i+2) regs -> drains B(i+1) too
      GLDSB(i + 2, cur);
      if (i + 3 < 47) LOADA(i + 3);
      asm volatile("s_waitcnt lgkmcnt(0)" ::: "memory");   // ds_writes visible
    } else {
      asm volatile("s_waitcnt vmcnt(0) lgkmcnt(0)" ::: "memory");  // tail drain
    }
    BARRIER();
  }
  #undef LOADA
  #undef WRITEA
  #undef GLDSB
  #undef BARRIER
  // merge K-halves (verbatim v7)
  float* red = (float*)sbuf;
  int pp = wr * 2 + wc;
  if (ksw){
    #pragma unroll
    for (int m = 0; m < 2; ++m)
      #pragma unroll
      for (int n = 0; n < 2; ++n)
        #pragma unroll
        for (int r = 0; r < 4; ++r)
          red[((((m*2+n)*4 + r) << 8) + (pp << 6)) + lane] = acc[m][n][r];
  }
  __syncthreads();
  if (!ksw){
    #pragma unroll
    for (int m = 0; m < 2; ++m)
      #pragma unroll
      for (int n = 0; n < 2; ++n){
        #pragma unroll
        for (int r = 0; r < 4; ++r)
          acc[m][n][r] += red[((((m*2+n)*4 + r) << 8) + (pp << 6)) + lane];
        int row = bm + wr * 32 + m * 16 + kq * 4;
        int col = bn + wc * 32 + n * 16 + r16;
        float* o = Hh + (size_t)row * D1 + col;
        #pragma unroll
        for (int r = 0; r < 4; ++r) o[(size_t)r * D1] = acc[m][n][r];
      }
  }
}

// ---------------------------------------------------------------------------
// FALLBACK GEMM (proven): in-kernel split, 64x64 tile
// ---------------------------------------------------------------------------
__global__ __launch_bounds__(256) void gemm_h_split(const float* __restrict__ X,
    const float* __restrict__ Wc, float* __restrict__ Hh){
  __shared__ u16 Ahs[64][40], Als[64][40], Bhs[64][40], Bls[64][40];
  int t = threadIdx.x, lane = t & 63, wave = t >> 6;
  int wr = wave >> 1, wcc = wave & 1;
  int bm = blockIdx.x * 64, bn = blockIdx.y * 64;
  f32x4 acc[2][2] = {};
  int arow = t >> 2, akc = (t & 3) << 3;
  int brow = t >> 3, bnc = (t & 7) << 3;
  for (int k0 = 0; k0 < IND; k0 += 32){
    float va[8];
    size_t abase = (size_t)(bm + arow) * IND + k0 + akc;
    if (k0 + akc + 8 <= IND){
      float4 r0 = *(const float4*)(X + abase);
      float4 r1 = *(const float4*)(X + abase + 4);
      va[0]=r0.x; va[1]=r0.y; va[2]=r0.z; va[3]=r0.w;
      va[4]=r1.x; va[5]=r1.y; va[6]=r1.z; va[7]=r1.w;
    } else {
      #pragma unroll
      for (int j = 0; j < 8; ++j){
        int k = k0 + akc + j;
        va[j] = (k < IND) ? X[abase + j] : 0.f;
      }
    }
    #pragma unroll
    for (int j = 0; j < 8; ++j){
      u16 hb = f2b(va[j]);
      Ahs[arow][akc + j] = hb;
      Als[arow][akc + j] = f2b(va[j] - b2f(hb));
    }
    {
      int gk = k0 + brow;
      float vb[8];
      if (gk < IND){
        const float* wp = Wc + (size_t)gk * D1 + bn + bnc;
        float4 r0 = *(const float4*)wp;
        float4 r1 = *(const float4*)(wp + 4);
        vb[0]=r0.x; vb[1]=r0.y; vb[2]=r0.z; vb[3]=r0.w;
        vb[4]=r1.x; vb[5]=r1.y; vb[6]=r1.z; vb[7]=r1.w;
      } else {
        #pragma unroll
        for (int j = 0; j < 8; ++j) vb[j] = 0.f;
      }
      #pragma unroll
      for (int j = 0; j < 8; ++j){
        u16 hb = f2b(vb[j]);
        Bhs[bnc + j][brow] = hb;
        Bls[bnc + j][brow] = f2b(vb[j] - b2f(hb));
      }
    }
    __syncthreads();
    int r16 = lane & 15, kq = (lane >> 4) << 3;
    short8 a0h = *(const short8*)&Ahs[wr*32      + r16][kq];
    short8 a1h = *(const short8*)&Ahs[wr*32 + 16 + r16][kq];
    short8 a0l = *(const short8*)&Als[wr*32      + r16][kq];
    short8 a1l = *(const short8*)&Als[wr*32 + 16 + r16][kq];
    short8 b0h = *(const short8*)&Bhs[wcc*32      + r16][kq];
    short8 b1h = *(const short8*)&Bhs[wcc*32 + 16 + r16][kq];
    short8 b0l = *(const short8*)&Bls[wcc*32      + r16][kq];
    short8 b1l = *(const short8*)&Bls[wcc*32 + 16 + r16][kq];
    acc[0][0] = __builtin_amdgcn_mfma_f32_16x16x32_bf16(a0h, b0h, acc[0][0], 0, 0, 0);
    acc[0][1] = __builtin_amdgcn_mfma_f32_16x16x32_bf16(a0h, b1h, acc[0][1], 0, 0, 0);
    acc[1][0] = __builtin_amdgcn_mfma_f32_16x16x32_bf16(a1h, b0h, acc[1][0], 0, 0, 0);
    acc[1][1] = __builtin_amdgcn_mfma_f32_16x16x32_bf16(a1h, b1h, acc[1][1], 0, 0, 0);
    acc[0][0] = __builtin_amdgcn_mfma_f32_16x16x32_bf16(a0h, b0l, acc[0][0], 0, 0, 0);
    acc[0][1] = __builtin_amdgcn_mfma_f32_16x16x32_bf16(a0h, b1l, acc[0][1], 0, 0, 0);
    acc[1][0] = __builtin_amdgcn_mfma_f32_16x16x32_bf16(a1h, b0l, acc[1][0], 0, 0, 0);
    acc[1][1] = __builtin_amdgcn_mfma_f32_16x16x32_bf16(a1h, b1l, acc[1][1], 0, 0, 0);
    acc[0][0] = __builtin_amdgcn_mfma_f32_16x16x32_bf16(a0l, b0h, acc[0][0], 0, 0, 0);
    acc[0][1] = __builtin_amdgcn_mfma_f32_16x16x32_bf16(a0l, b1h, acc[0][1], 0, 0, 0);
    acc[1][0] = __builtin_amdgcn_mfma_f32_16x16x32_bf16(a1l, b0h, acc[1][0], 0, 0, 0);
    acc[1][1] = __builtin_amdgcn_mfma_f32_16x16x32_bf16(a1l, b1h, acc[1][1], 0, 0, 0);
    __syncthreads();
  }
  int cr = (lane >> 4) << 2, cc = lane & 15;
  for (int i = 0; i < 2; ++i) for (int j = 0; j < 2; ++j){
    int row = bm + wr*32 + i*16 + cr;
    int col = bn + wcc*32 + j*16 + cc;
    float* o = Hh + (size_t)row * D1 + col;
    for (int r = 0; r < 4; ++r) o[(size_t)r * D1] = acc[i][j][r];
  }
}

// ---------------------------------------------------------------------------
// h [4096,512] fp32 -> h16 bf16 (elementwise)
// ---------------------------------------------------------------------------
__global__ __launch_bounds__(256) void cvt_h16(const float* __restrict__ h,
    u16* __restrict__ h16){
  size_t i = ((size_t)blockIdx.x * 256 + threadIdx.x) * 8;
  float4 va = *(const float4*)(h + i);
  float4 vb = *(const float4*)(h + i + 4);
  u16 q[8] = { f2b(va.x), f2b(va.y), f2b(va.z), f2b(va.w),
               f2b(vb.x), f2b(vb.y), f2b(vb.z), f2b(vb.w) };
  *(uint4*)(h16 + i) = *(uint4*)q;
}

// ---------------------------------------------------------------------------
// layer-1 logits, vectorized
// ---------------------------------------------------------------------------
__global__ __launch_bounds__(256) void evec128(const float* __restrict__ hsrc,
    const float* __restrict__ as_, const float* __restrict__ ad_,
    float* __restrict__ es, float* __restrict__ ed){
  int idx = blockIdx.x * 256 + threadIdx.x;
  if (idx >= NN * HH) return;
  int h = idx & 3;
  const float4* hp = (const float4*)(hsrc + (size_t)idx * C1);
  const float4* ap = (const float4*)(as_ + h * C1);
  const float4* dp = (const float4*)(ad_ + h * C1);
  float s1 = 0.f, s2 = 0.f;
  #pragma unroll
  for (int c = 0; c < 32; ++c){
    float4 v = hp[c], a = ap[c], d = dp[c];
    s1 += v.x*a.x + v.y*a.y + v.z*a.z + v.w*a.w;
    s2 += v.x*d.x + v.y*d.y + v.z*d.z + v.w*d.w;
  }
  es[idx] = s1; ed[idx] = s2;
}

// ---------------------------------------------------------------------------
// CSR build
// ---------------------------------------------------------------------------
__global__ void zero_kernel(int* p, int n){
  int i = blockIdx.x * blockDim.x + threadIdx.x;
  if (i < n) p[i] = 0;
}
__global__ void hist_kernel(const int* __restrict__ dstA, int* __restrict__ deg){
  int e = blockIdx.x * blockDim.x + threadIdx.x;
  if (e < ETOT){
    int d = (e < EE) ? dstA[e] : (e - EE);
    atomicAdd(&deg[d & (NN-1)], 1);
  }
}
__global__ __launch_bounds__(1024) void scan_kernel(const int* __restrict__ deg,
    int* __restrict__ off, int* __restrict__ cur){
  __shared__ int wsum[16];
  int t = threadIdx.x, lane = t & 63, wv = t >> 6;
  int v0 = deg[t*4], v1 = deg[t*4+1], v2 = deg[t*4+2], v3 = deg[t*4+3];
  int s = v0 + v1 + v2 + v3;
  int sc = s;
  #pragma unroll
  for (int o = 1; o < 64; o <<= 1){
    int y = __shfl_up(sc, o);
    if (lane >= o) sc += y;
  }
  if (lane == 63) wsum[wv] = sc;
  __syncthreads();
  int base = 0;
  #pragma unroll
  for (int i = 0; i < 16; ++i) base += (i < wv) ? wsum[i] : 0;
  int excl = base + sc - s;
  int a0 = excl, a1 = a0 + v0, a2 = a1 + v1, a3 = a2 + v2;
  off[t*4] = a0; off[t*4+1] = a1; off[t*4+2] = a2; off[t*4+3] = a3;
  cur[t*4] = a0; cur[t*4+1] = a1; cur[t*4+2] = a2; cur[t*4+3] = a3;
  if (t == 1023) off[4096] = base + sc;
}
__global__ void scatter_kernel(const int* __restrict__ srcA, const int* __restrict__ dstA,
    int* __restrict__ cur, int* __restrict__ sidx){
  int e = blockIdx.x * blockDim.x + threadIdx.x;
  if (e < ETOT){
    int s, d;
    if (e < EE){ s = srcA[e]; d = dstA[e]; } else { s = d = e - EE; }
    int pos = atomicAdd(&cur[d & (NN-1)], 1);
    pos = min(max(pos, 0), ETOT - 1);
    sidx[pos] = s & (NN-1);
  }
}

// ---------------------------------------------------------------------------
// sparse layer 1: single pass, unnormalized accumulate, bf16 h gather.
// ---------------------------------------------------------------------------
__global__ __launch_bounds__(256) void sparse1(const u16* __restrict__ h16,
    const float* __restrict__ es, const float* __restrict__ ed,
    const int* __restrict__ off, const int* __restrict__ sidx,
    const float* __restrict__ bias, u16* __restrict__ x1h, u16* __restrict__ x1l){
  int n = blockIdx.x, t = threadIdx.x, w = t >> 6;
  int o0 = off[n], deg = off[n+1] - o0;
  deg = min(max(deg, 0), ETOT);
  float edn = ed[n * HH + w];
  float dsum = 1e-16f, a0 = 0.f, a1 = 0.f;
  for (int e = 0; e < deg; ++e){
    int s = sidx[o0 + e] & (NN-1);
    float we = __expf(lrelu(es[s*HH + w] + edn));
    unsigned pk = *(const unsigned*)(h16 + ((size_t)s << 9) + 2*t);
    a0 = fmaf(we, b2f((u16)(pk & 0xffff)), a0);
    a1 = fmaf(we, b2f((u16)(pk >> 16)), a1);
    dsum += we;
  }
  float inv = 1.0f / dsum;
  float v0 = a0 * inv + bias[2*t];
  float v1 = a1 * inv + bias[2*t + 1];
  u16 h0 = f2b(v0), h1 = f2b(v1);
  u16 l0 = f2b(v0 - b2f(h0)), l1 = f2b(v1 - b2f(h1));
  size_t o = ((size_t)n << 9) + 2*t;
  *(unsigned*)(x1h + o) = (unsigned)h0 | ((unsigned)h1 << 16);
  *(unsigned*)(x1l + o) = (unsigned)l0 | ((unsigned)l1 << 16);
}

// ---------------------------------------------------------------------------
// sparse layer 2: one wave per (node, branch); fp32 gather (direct output)
// ---------------------------------------------------------------------------
struct Sp2 { const float* h[2]; const float* es[2]; const float* ed[2];
             const float* bias[2]; float* out[2]; };
__global__ __launch_bounds__(64) void sparse2(Sp2 a,
    const int* __restrict__ off, const int* __restrict__ sidx){
  int n = blockIdx.x, sel = blockIdx.y;
  int lane = threadIdx.x, hh = lane >> 4;
  const float* hsrc = a.h[sel];
  const float* es = a.es[sel];
  const float* ed = a.ed[sel];
  int o0 = off[n], deg = off[n+1] - o0;
  deg = min(max(deg, 0), ETOT);
  float edn = ed[n * HH + hh];
  float dsum = 1e-16f, acc = 0.f;
  for (int e = 0; e < deg; ++e){
    int s = sidx[o0 + e] & (NN-1);
    float we = __expf(lrelu(es[s*HH + hh] + edn));
    acc = fmaf(we, hsrc[(size_t)s * 64 + lane], acc);
    dsum += we;
  }
  float v = acc / dsum;
  v += __shfl_xor(v, 16);
  v += __shfl_xor(v, 32);
  if (lane < 16) a.out[sel][(size_t)n * C2 + lane] = v * 0.25f + a.bias[sel][lane];
}

// ---------------------------------------------------------------------------
// fused small GEMMs + layer-2 logits — split-bf16 MFMA.
// ---------------------------------------------------------------------------
struct GsA {
  const u16* x1h; const u16* x1l; const u16* x2h; const u16* x2l;
  const u16* Wh; const u16* Wl;
  float* hm1; float* hs1; float* hm2; float* hs2;
  const float* AMS; const float* AMD; const float* ASS; const float* ASD;
  float* em1s; float* em1d; float* es1s; float* es1d;
  float* em2s; float* em2d; float* es2s; float* es2d;
};
__global__ __launch_bounds__(256) void gemm_small_fused(GsA a){
  __shared__ u16 sAh[32*64], sAl[32*64], sBh[128*64], sBl[128*64];  // 40 KB
  int t = threadIdx.x, lane = t & 63;
  int wv = __builtin_amdgcn_readfirstlane(t >> 6);
  int src = blockIdx.y;
  int bm = blockIdx.x * 32;
  const u16* xh = src ? a.x2h : a.x1h;
  const u16* xl = src ? a.x2l : a.x1l;
  f32x4 acc[2][2] = {};
  int sarow = t >> 3, sac = (t & 7) ^ (sarow & 7);
  const char* gAh = (const char*)(xh + (size_t)(bm + sarow) * 512) + sac * 16;
  const char* gAl = (const char*)(xl + (size_t)(bm + sarow) * 512) + sac * 16;
  char* lAh = (char*)sAh + t * 16;
  char* lAl = (char*)sAl + t * 16;
  const char* gBh[4]; const char* gBl[4];
  #pragma unroll
  for (int q = 0; q < 4; ++q){
    int id = q * 256 + t;
    int br = id >> 3, bc = (id & 7) ^ (br & 7);
    gBh[q] = (const char*)(a.Wh + (size_t)br * 512) + bc * 16;
    gBl[q] = (const char*)(a.Wl + (size_t)br * 512) + bc * 16;
  }
  int r16 = lane & 15, kq = lane >> 4;
  int aoff[2][2], boff[2][2];
  #pragma unroll
  for (int m = 0; m < 2; ++m)
    #pragma unroll
    for (int ks = 0; ks < 2; ++ks){
      int arow = m * 16 + r16;
      int cc = ks * 4 + kq;
      aoff[m][ks] = arow * 128 + ((cc ^ (arow & 7)) * 16);
    }
  #pragma unroll
  for (int n = 0; n < 2; ++n)
    #pragma unroll
    for (int ks = 0; ks < 2; ++ks){
      int brow = wv * 32 + n * 16 + r16;
      int cc = ks * 4 + kq;
      boff[n][ks] = brow * 128 + ((cc ^ (brow & 7)) * 16);
    }
  for (int kb = 0; kb < 1024; kb += 128){
    glds16(gAh + kb, lAh);
    glds16(gAl + kb, lAl);
    #pragma unroll
    for (int q = 0; q < 4; ++q){
      glds16(gBh[q] + kb, (char*)sBh + (q * 256 + t) * 16);
      glds16(gBl[q] + kb, (char*)sBl + (q * 256 + t) * 16);
    }
    __syncthreads();
    #pragma unroll
    for (int ks = 0; ks < 2; ++ks){
      short8 ah[2], al[2], bh[2], bl[2];
      #pragma unroll
      for (int m = 0; m < 2; ++m){
        ah[m] = *(const short8*)((const char*)sAh + aoff[m][ks]);
        al[m] = *(const short8*)((const char*)sAl + aoff[m][ks]);
      }
      #pragma unroll
      for (int n = 0; n < 2; ++n){
        bh[n] = *(const short8*)((const char*)sBh + boff[n][ks]);
        bl[n] = *(const short8*)((const char*)sBl + boff[n][ks]);
      }
      #pragma unroll
      for (int m = 0; m < 2; ++m)
        #pragma unroll
        for (int n = 0; n < 2; ++n){
          acc[m][n] = __builtin_amdgcn_mfma_f32_16x16x32_bf16(ah[m], bh[n], acc[m][n], 0, 0, 0);
          acc[m][n] = __builtin_amdgcn_mfma_f32_16x16x32_bf16(ah[m], bl[n], acc[m][n], 0, 0, 0);
          acc[m][n] = __builtin_amdgcn_mfma_f32_16x16x32_bf16(al[m], bh[n], acc[m][n], 0, 0, 0);
        }
    }
    __syncthreads();
  }
  #pragma unroll
  for (int m = 0; m < 2; ++m){
    #pragma unroll
    for (int n = 0; n < 2; ++n){
      int colB = wv * 32 + n * 16;
      int half = colB >> 6;
      int colh = (colB & 63) + r16;
      int hh = (colB & 63) >> 4;
      int row0 = bm + m * 16 + kq * 4;
      float* o = (src ? (half ? a.hs2 : a.hm2) : (half ? a.hs1 : a.hm1))
                 + (size_t)row0 * 64 + colh;
      #pragma unroll
      for (int r = 0; r < 4; ++r) o[(size_t)r * 64] = acc[m][n][r];
      const float* AS = half ? a.ASS : a.AMS;
      const float* AD = half ? a.ASD : a.AMD;
      float av = AS[colh], dv = AD[colh];
      float* esP = src ? (half ? a.es2s : a.em2s) : (half ? a.es1s : a.em1s);
      float* edP = src ? (half ? a.es2d : a.em2d) : (half ? a.es1d : a.em1d);
      #pragma unroll
      for (int r = 0; r < 4; ++r){
        float vs = acc[m][n][r] * av;
        float vd = acc[m][n][r] * dv;
        #pragma unroll
        for (int msk = 1; msk < 16; msk <<= 1){
          vs += __shfl_xor(vs, msk);
          vd += __shfl_xor(vd, msk);
        }
        if (r16 == 0){
          int rw = row0 + r;
          esP[rw * HH + hh] = vs;
          edP[rw * HH + hh] = vd;
        }
      }
    }
  }
}

// ---------------------------------------------------------------------------
// rank-based sort
// ---------------------------------------------------------------------------
struct RkA { const float* in[2]; float* us[2]; int* pm[2]; };
__global__ __launch_bounds__(1024) void rank_kernel(RkA a){
  int sid = blockIdx.y;
  int sel = sid >> 2, h = sid & 3;
  const float* evals = a.in[sel];
  __shared__ u64 K[NN];
  __shared__ int red[1024];
  int t = threadIdx.x;
  for (int i = t; i < NN; i += 1024){
    unsigned x = __float_as_uint(evals[i*HH + h]);
    x = (x & 0x80000000u) ? ~x : (x | 0x80000000u);
    K[i] = ((u64)x << 32) | (unsigned)i;
  }
  __syncthreads();
  int jl = t & 63, sp = t >> 6;
  int j = blockIdx.x * 64 + jl;
  u64 myk = K[j];
  int cnt = 0;
  int k0 = sp * 256;
  #pragma unroll 8
  for (int i = 0; i < 256; ++i)
    cnt += (K[k0 + i] < myk) ? 1 : 0;
  red[t] = cnt;
  __syncthreads();
  if (sp == 0){
    int rank = 0;
    #pragma unroll
    for (int s = 0; s < 16; ++s) rank += red[jl + 64*s];
    a.us[sel][h*NN + rank] = evals[j*HH + h];
    a.pm[sel][h*NN + rank] = j;
  }
}

// ---------------------------------------------------------------------------
// prefix path v2: row-parallel two-pass scan with COALESCED P writes.
// ---------------------------------------------------------------------------
struct PfxN { const float* hsrc[2]; const int* pm[2]; const float* us[2];
              float* T1; float* T2; float* P1[2]; float* P2[2]; };

template<int C, int CW, int G, int KPER, int NCH>
__global__ __launch_bounds__(512) void pfx_tot(PfxN a){
  constexpr int Cp = C + 1;
  constexpr int CHUNK = G * KPER;
  constexpr int L = G * NCH;
  __shared__ float E1[CHUNK], E2[CHUNK];
  __shared__ int PM[CHUNK];
  int sel = blockIdx.y;
  int h = blockIdx.x / NCH, ch = blockIdx.x % NCH;
  int tid = threadIdx.x;
  const float* us = a.us[sel] + h * NN + ch * CHUNK;
  const int* pm = a.pm[sel] + h * NN + ch * CHUNK;
  for (int tt = tid; tt < CHUNK; tt += 512){
    float u = us[tt];
    E1[tt] = __expf(u); E2[tt] = __expf(0.2f * u);
    PM[tt] = pm[tt] & (NN - 1);
  }
  __syncthreads();
  int g = tid / C, c = tid % C;
  const float* hs = a.hsrc[sel];
  float s1 = 0.f, s2 = 0.f, d1 = 0.f, d2 = 0.f;
  #pragma unroll
  for (int j = 0; j < KPER; ++j){
    int kk = g * KPER + j;
    float v = hs[(size_t)PM[kk] * CW + h * C + c];
    s1 = fmaf(E1[kk], v, s1); s2 = fmaf(E2[kk], v, s2);
    d1 += E1[kk]; d2 += E2[kk];
  }
  int pos = ch * G + g;
  size_t col = (size_t)(sel * HH + h) * Cp + c;
  a.T1[col * L + pos] = s1;
  a.T2[col * L + pos] = s2;
  if (c == 0){
    size_t colD = (size_t)(sel * HH + h) * Cp + C;
    a.T1[colD * L + pos] = d1;
    a.T2[colD * L + pos] = d2;
  }
}

template<int C>
__global__ __launch_bounds__(64) void pfx_scan(PfxN a, int L){
  constexpr int Cp = C + 1;
  int sel = blockIdx.y;
  int col = blockIdx.x;
  int h = col / Cp, c = col % Cp;
  size_t gcol = (size_t)(sel * HH + h) * Cp + c;
  int lane = threadIdx.x;
  float run1 = 0.f, run2 = 0.f;
  for (int p0 = 0; p0 < L; p0 += 64){
    size_t idx = gcol * (size_t)L + p0 + lane;
    float o1 = a.T1[idx], o2 = a.T2[idx];
    float a1 = o1, a2 = o2;
    #pragma unroll
    for (int o = 1; o < 64; o <<= 1){
      float y1 = __shfl_up(a1, o), y2 = __shfl_up(a2, o);
      if (lane >= o){ a1 += y1; a2 += y2; }
    }
    a.T1[idx] = run1 + a1 - o1;
    a.T2[idx] = run2 + a2 - o2;
    run1 += __shfl(a1, 63);
    run2 += __shfl(a2, 63);
  }
  if (lane == 0){
    size_t base = (size_t)h * (NN + 1);
    a.P1[sel][(base + NN) * Cp + c] = run1;
    a.P2[sel][(base + NN) * Cp + c] = run2;
  }
}

template<int C, int CW, int G, int KPER, int NCH>
__global__ __launch_bounds__(512) void pfx_emit(PfxN a){
  constexpr int Cp = C + 1;
  constexpr int CHUNK = G * KPER;
  constexpr int L = G * NCH;
  __shared__ float E1[CHUNK], E2[CHUNK];
  __shared__ int PM[CHUNK];
  int sel = blockIdx.y;
  int h = blockIdx.x / NCH, ch = blockIdx.x % NCH;
  int tid = threadIdx.x;
  const float* us = a.us[sel] + h * NN + ch * CHUNK;
  const int* pm = a.pm[sel] + h * NN + ch * CHUNK;
  for (int tt = tid; tt < CHUNK; tt += 512){
    float u = us[tt];
    E1[tt] = __expf(u); E2[tt] = __expf(0.2f * u);
    PM[tt] = pm[tt] & (NN - 1);
  }
  __syncthreads();
  int g = tid / C, c = tid % C;
  const float* hs = a.hsrc[sel];
  float* P1 = a.P1[sel];
  float* P2 = a.P2[sel];
  int pos = ch * G + g;
  size_t col = (size_t)(sel * HH + h) * Cp + c;
  float r1 = a.T1[col * L + pos];
  float r2 = a.T2[col * L + pos];
  float rD1 = 0.f, rD2 = 0.f;
  if (c == 0){
    size_t colD = (size_t)(sel * HH + h) * Cp + C;
    rD1 = a.T1[colD * L + pos];
    rD2 = a.T2[colD * L + pos];
  }
  size_t hb = (size_t)h * (NN + 1) + ch * CHUNK + g * KPER;
  #pragma unroll
  for (int j = 0; j < KPER; ++j){
    int kk = g * KPER + j;
    float v = hs[(size_t)PM[kk] * CW + h * C + c];
    P1[(hb + j) * Cp + c] = r1;
    P2[(hb + j) * Cp + c] = r2;
    r1 = fmaf(E1[kk], v, r1);
    r2 = fmaf(E2[kk], v, r2);
    if (c == 0){
      P1[(hb + j) * Cp + C] = rD1;
      P2[(hb + j) * Cp + C] = rD2;
      rD1 += E1[kk]; rD2 += E2[kk];
    }
  }
}

// ---------------------------------------------------------------------------
// dense output via separable leaky-relu softmax
// ---------------------------------------------------------------------------
template<int C, bool MEAN>
__device__ __forceinline__ void dense_body(const float* __restrict__ P1,
    const float* __restrict__ P2, const float* __restrict__ usort,
    const float* __restrict__ ed, const float* __restrict__ bias,
    float* __restrict__ outF, u16* __restrict__ outH, u16* __restrict__ outL, int i){
  constexpr int Cp = C + 1;
  constexpr int NC = HH * C;
  int t = threadIdx.x;
  __shared__ float Ed[HH], E2d[HH], Den[HH];
  __shared__ int   Kh[HH];
  __shared__ float vals[NC > 256 ? 1 : NC];
  if (t < HH){
    float d = ed[i*HH + t];
    float target = -d;
    const float* us = usort + t * NN;
    int lo = 0, hi = NN;
    while (lo < hi){ int mid = (lo + hi) >> 1; if (us[mid] < target) lo = mid + 1; else hi = mid; }
    Kh[t] = lo;
    float e1 = __expf(d), e2 = __expf(0.2f * d);
    Ed[t] = e1; E2d[t] = e2;
    size_t base = (size_t)t * (NN + 1);
    float p1N = P1[(base + NN) * Cp + C];
    float p1k = P1[(base + lo) * Cp + C];
    float p2k = P2[(base + lo) * Cp + C];
    Den[t] = e1 * (p1N - p1k) + e2 * p2k;
  }
  __syncthreads();
  if (!MEAN){
    for (int ch = t; ch < NC; ch += 256){
      int h = ch / C, c = ch % C;
      size_t base = (size_t)h * (NN + 1);
      float p1N = P1[(base + NN)    * Cp + c];
      float p1k = P1[(base + Kh[h]) * Cp + c];
      float p2k = P2[(base + Kh[h]) * Cp + c];
      float num = Ed[h] * (p1N - p1k) + E2d[h] * p2k;
      float val = num / Den[h] + bias[ch];
      u16 hb = f2b(val);
      outH[(size_t)i * NC + ch] = hb;
      outL[(size_t)i * NC + ch] = f2b(val - b2f(hb));
    }
  } else {
    if (t < NC){
      int h = t / C, c = t % C;
      size_t base = (size_t)h * (NN + 1);
      float p1N = P1[(base + NN)    * Cp + c];
      float p1k = P1[(base + Kh[h]) * Cp + c];
      float p2k = P2[(base + Kh[h]) * Cp + c];
      vals[t] = (Ed[h] * (p1N - p1k) + E2d[h] * p2k) / Den[h];
    }
    __syncthreads();
    if (t < C){
      float z = (vals[t] + vals[C + t] + vals[2*C + t] + vals[3*C + t]) * 0.25f + bias[t];
      outF[(size_t)i * C + t] = z;
    }
  }
}

__global__ __launch_bounds__(256) void dense_out1(const float* __restrict__ P1,
    const float* __restrict__ P2, const float* __restrict__ usort,
    const float* __restrict__ ed, const float* __restrict__ bias,
    u16* __restrict__ outH, u16* __restrict__ outL){
  dense_body<C1, false>(P1, P2, usort, ed, bias, nullptr, outH, outL, blockIdx.x);
}

struct Dn2 { const float* P1[2]; const float* P2[2]; const float* us[2];
             const float* ed[2]; const float* bias[2]; float* out[2]; };
__global__ __launch_bounds__(256) void dense_out2(Dn2 a){
  int s = blockIdx.y;
  dense_body<C2, true>(a.P1[s], a.P2[s], a.us[s], a.ed[s], a.bias[s], a.out[s],
                       nullptr, nullptr, blockIdx.x);
}

// ---------------------------------------------------------------------------
extern "C" void kernel_launch(void* const* d_in, const int* in_sizes, int n_in,
                              void* d_out, int out_size, void* d_ws, size_t ws_size,
                              hipStream_t stream){
  const float* X   = (const float*)d_in[0];
  const int*   EI  = (const int*)d_in[1];
  const float* W1  = (const float*)d_in[3];
  const float* A1S = (const float*)d_in[4];
  const float* A1D = (const float*)d_in[5];
  const float* B1  = (const float*)d_in[6];
  const float* WM  = (const float*)d_in[7];
  const float* AMS = (const float*)d_in[8];
  const float* AMD = (const float*)d_in[9];
  const float* BM  = (const float*)d_in[10];
  const float* WS  = (const float*)d_in[11];
  const float* ASS = (const float*)d_in[12];
  const float* ASD = (const float*)d_in[13];
  const float* BS  = (const float*)d_in[14];
  float* OUT = (float*)d_out;
  (void)in_sizes; (void)n_in;

  if (ws_size < (size_t)56 * 1024 * 1024){
    zero_out_kernel<<<dim3((out_size + 255)/256), 256, 0, stream>>>(OUT, out_size);
    return;
  }
  bool fast = (ws_size >= (size_t)68 * 1024 * 1024);

  const size_t MB = 1024 * 1024;
  char* w = (char*)d_ws;
  size_t o = 0;
  auto alloc = [&](size_t bytes) -> void* {
    void* p = w + o;
    o += (bytes + 255) & ~(size_t)255;
    return p;
  };
  int*   deg  = (int*)  alloc(NN * 4);
  int*   coff = (int*)  alloc((NN + 1) * 4);
  int*   cur  = (int*)  alloc(NN * 4);
  int*   sidx = (int*)  alloc((size_t)ETOT * 4);
  float* e1s  = (float*)alloc(NN * HH * 4);
  float* e1d  = (float*)alloc(NN * HH * 4);
  float* us1  = (float*)alloc(HH * NN * 4);
  int*   pm1  = (int*)  alloc(HH * NN * 4);
  float* em1s = (float*)alloc(NN * HH * 4);
  float* em1d = (float*)alloc(NN * HH * 4);
  float* es1s = (float*)alloc(NN * HH * 4);
  float* es1d = (float*)alloc(NN * HH * 4);
  float* em2s = (float*)alloc(NN * HH * 4);
  float* em2d = (float*)alloc(NN * HH * 4);
  float* es2s = (float*)alloc(NN * HH * 4);
  float* es2d = (float*)alloc(NN * HH * 4);
  float* us2m = (float*)alloc(HH * NN * 4);
  int*   pm2m = (int*)  alloc(HH * NN * 4);
  float* us2s = (float*)alloc(HH * NN * 4);
  int*   pm2s = (int*)  alloc(HH * NN * 4);
  u16*   Wh2  = (u16*)  alloc(128 * 512 * 2);
  u16*   Wl2  = (u16*)  alloc(128 * 512 * 2);
  float* h    = (float*)alloc((size_t)NN * D1 * 4);
  char*  BIG  = w + o;
  // --- phase A (GEMM W staging, dead after gemm_mfma) ---
  u16* Whi = (u16*)BIG;                         // 512*3008*2 ~ 2.94 MB
  u16* Wlo = (u16*)(BIG + 4*MB);
  // --- phase B (post-GEMM; x1/x2 stored as split bf16 hi/lo) ---
  u16*   x1h = (u16*)  (BIG + 0*MB);
  u16*   x1l = (u16*)  (BIG + 4*MB);
  u16*   x2h = (u16*)  (BIG + 8*MB);
  u16*   x2l = (u16*)  (BIG + 12*MB);
  float* T1a = (float*)(BIG + 16*MB);           // layer-1 prefix totals
  float* T2a = (float*)(BIG + 17*MB);
  u16*   h16 = (u16*)  (BIG + 24*MB);
  float* P1a = (float*)(BIG + 28*MB);
  float* P2a = (float*)(BIG + 37*MB);
  // --- phase C (from gemm_small_fused on) ---
  float* hm1  = (float*)(BIG + 16*MB);
  float* hs1  = (float*)(BIG + 17*MB);
  float* hm2  = (float*)(BIG + 18*MB);
  float* hs2  = (float*)(BIG + 19*MB);
  float* P1m  = (float*)(BIG + 20*MB);
  float* P2m  = (float*)(BIG + 21*MB + 512*1024);
  float* P1s  = (float*)(BIG + 23*MB);
  float* P2s  = (float*)(BIG + 24*MB + 512*1024);
  float* T1b  = (float*)(BIG + 26*MB);          // layer-2 prefix totals
  float* T2b  = (float*)(BIG + 26*MB + 512*1024);

  const int* srcA = EI;
  const int* dstA = EI + EE;

  // 0. small-W conversions
  cvtW2_kernel<<<dim3(8, 2), 256, 0, stream>>>(WM, WS, Wh2, Wl2);
  // 1. h = X @ W1
  if (fast){
    cvtW1_kernel<<<dim3(47*8), 256, 0, stream>>>(W1, Whi, Wlo);
    gemm_mfma<<<dim3(NN/64, D1/64), 512, 0, stream>>>(X, Whi, Wlo, h);
  } else {
    gemm_h_split<<<dim3(NN/64, D1/64), 256, 0, stream>>>(X, W1, h);
  }
  // 2. bf16 copy; layer-1 logits
  cvt_h16<<<dim3(1024), 256, 0, stream>>>(h, h16);
  evec128<<<dim3(NN*HH/256), 256, 0, stream>>>(h, A1S, A1D, e1s, e1d);
  // 3. CSR
  zero_kernel<<<dim3(16), 256, 0, stream>>>(deg, NN);
  hist_kernel<<<dim3((ETOT + 255)/256), 256, 0, stream>>>(dstA, deg);
  scan_kernel<<<dim3(1), 1024, 0, stream>>>(deg, coff, cur);
  scatter_kernel<<<dim3((ETOT + 255)/256), 256, 0, stream>>>(srcA, dstA, cur, sidx);
  // 4. sparse layer 1 -> x1 (split bf16)
  sparse1<<<dim3(NN), 256, 0, stream>>>(h16, e1s, e1d, coff, sidx, B1, x1h, x1l);
  // 5. dense layer 1 -> x2 (split bf16); prefix v2 (coalesced writes)
  {
    RkA ra; ra.in[0] = e1s; ra.in[1] = e1s; ra.us[0] = us1; ra.us[1] = us1;
    ra.pm[0] = pm1; ra.pm[1] = pm1;
    rank_kernel<<<dim3(64, 4), 1024, 0, stream>>>(ra);
    PfxN pa;
    pa.hsrc[0] = h;  pa.hsrc[1] = h;
    pa.pm[0] = pm1;  pa.pm[1] = pm1;
    pa.us[0] = us1;  pa.us[1] = us1;
    pa.T1 = T1a; pa.T2 = T2a;
    pa.P1[0] = P1a; pa.P1[1] = P1a;
    pa.P2[0] = P2a; pa.P2[1] = P2a;
    pfx_tot<C1, D1, 4, 16, 64><<<dim3(HH*64, 1), 512, 0, stream>>>(pa);
    pfx_scan<C1><<<dim3(HH*(C1+1), 1), 64, 0, stream>>>(pa, 256);
    pfx_emit<C1, D1, 4, 16, 64><<<dim3(HH*64, 1), 512, 0, stream>>>(pa);
    dense_out1<<<dim3(NN), 256, 0, stream>>>(P1a, P2a, us1, e1d, B1, x2h, x2l);
  }
  // 6. fused projections + layer-2 logits (split-bf16 MFMA)
  {
    GsA ga;
    ga.x1h = x1h; ga.x1l = x1l; ga.x2h = x2h; ga.x2l = x2l;
    ga.Wh = Wh2; ga.Wl = Wl2;
    ga.hm1 = hm1; ga.hs1 = hs1; ga.hm2 = hm2; ga.hs2 = hs2;
    ga.AMS = AMS; ga.AMD = AMD; ga.ASS = ASS; ga.ASD = ASD;
    ga.em1s = em1s; ga.em1d = em1d; ga.es1s = es1s; ga.es1d = es1d;
    ga.em2s = em2s; ga.em2d = em2d; ga.es2s = es2s; ga.es2d = es2d;
    gemm_small_fused<<<dim3(NN/32, 2), 256, 0, stream>>>(ga);
  }
  // 7. sparse layer 2 -> z_mean1, z_log_std1
  {
    Sp2 sp;
    sp.h[0] = hm1; sp.h[1] = hs1; sp.es[0] = em1s; sp.es[1] = es1s;
    sp.ed[0] = em1d; sp.ed[1] = es1d; sp.bias[0] = BM; sp.bias[1] = BS;
    sp.out[0] = OUT; sp.out[1] = OUT + (size_t)NN*C2;
    sparse2<<<dim3(NN, 2), 64, 0, stream>>>(sp, coff, sidx);
  }
  // 8. dense layer 2 -> z_mean2, z_log_std2; prefix v2
  {
    RkA ra; ra.in[0] = em2s; ra.in[1] = es2s; ra.us[0] = us2m; ra.us[1] = us2s;
    ra.pm[0] = pm2m; ra.pm[1] = pm2s;
    rank_kernel<<<dim3(64, 8), 1024, 0, stream>>>(ra);
    PfxN pa;
    pa.hsrc[0] = hm2; pa.hsrc[1] = hs2;
    pa.pm[0] = pm2m;  pa.pm[1] = pm2s;
    pa.us[0] = us2m;  pa.us[1] = us2s;
    pa.T1 = T1b; pa.T2 = T2b;
    pa.P1[0] = P1m; pa.P1[1] = P1s;
    pa.P2[0] = P2m; pa.P2[1] = P2s;
    pfx_tot<C2, 64, 32, 8, 16><<<dim3(HH*16, 2), 512, 0, stream>>>(pa);
    pfx_scan<C2><<<dim3(HH*(C2+1), 2), 64, 0, stream>>>(pa, 512);
    pfx_emit<C2, 64, 32, 8, 16><<<dim3(HH*16, 2), 512, 0, stream>>>(pa);
    Dn2 dn;
    dn.P1[0] = P1m; dn.P1[1] = P1s; dn.P2[0] = P2m; dn.P2[1] = P2s;
    dn.us[0] = us2m; dn.us[1] = us2s; dn.ed[0] = em2d; dn.ed[1] = es2d;
    dn.bias[0] = BM; dn.bias[1] = BS;
    dn.out[0] = OUT + (size_t)2*NN*C2; dn.out[1] = OUT + (size_t)3*NN*C2;
    dense_out2<<<dim3(NN, 2), 256, 0, stream>>>(dn);
  }
}